// Round 1
// baseline (1565.479 us; speedup 1.0000x reference)
//
#include <hip/hip_runtime.h>
#include <math.h>

#define NROWS 4096
#define DIM   512
#define NCLS  64
#define CAP   128      // max class size (binomial max ~88; 128 is ~8 sigma safe)
#define PD    768

// ---------------- reduction helpers ----------------
__device__ __forceinline__ float waveReduce(float v) {
#pragma unroll
  for (int o = 32; o > 0; o >>= 1) v += __shfl_down(v, o);
  return v;
}

// valid on thread 0 only; blockDim.x multiple of 64, <= 256
__device__ __forceinline__ float blockReduce(float v) {
  __shared__ float sh[4];
  int lane = threadIdx.x & 63, wv = threadIdx.x >> 6;
  v = waveReduce(v);
  if (lane == 0) sh[wv] = v;
  __syncthreads();
  float t = 0.f;
  if (threadIdx.x == 0) {
    int nw = (blockDim.x + 63) >> 6;
    for (int i = 0; i < nw; ++i) t += sh[i];
  }
  return t;
}

// ---------------- misc ----------------
__global__ void k_zerof(float* p, int n) {
  for (int i = blockIdx.x * blockDim.x + threadIdx.x; i < n; i += gridDim.x * blockDim.x) p[i] = 0.f;
}

// class bucketing: stable (ascending row index) per class
__global__ void k_bucket(const int* __restrict__ labels, int* cnt, int* off, int* perm, int* clsp) {
  __shared__ int scnt[NCLS];
  int t = threadIdx.x;  // blockDim = 64
  int c = 0;
  for (int r = 0; r < NROWS; ++r) c += (labels[r] == t);
  scnt[t] = c;
  cnt[t] = c;
  __syncthreads();
  if (t == 0) {
    int s = 0;
    for (int i = 0; i < NCLS; ++i) { off[i] = s; s += scnt[i]; }
    off[NCLS] = s;
  }
  __syncthreads();
  int pos = off[t];
  for (int r = 0; r < NROWS; ++r)
    if (labels[r] == t) { perm[pos] = r; clsp[pos] = t; ++pos; }
}

// gather rows into class-sorted order + row inverse norms
__global__ __launch_bounds__(128) void k_gather(const float* __restrict__ G, const int* __restrict__ perm,
                                                float* __restrict__ Gp, float* __restrict__ invn) {
  __shared__ float red[2];
  int row = blockIdx.x, t = threadIdx.x;
  const float4* src = (const float4*)(G + (size_t)perm[row] * DIM);
  float4* dst = (float4*)(Gp + (size_t)row * DIM);
  float4 v = src[t];
  dst[t] = v;
  float ss = v.x * v.x + v.y * v.y + v.z * v.z + v.w * v.w;
  ss = waveReduce(ss);
  if ((t & 63) == 0) red[t >> 6] = ss;
  __syncthreads();
  if (t == 0) invn[row] = 1.f / fmaxf(sqrtf(red[0] + red[1]), 1e-12f);
}

// per-class cosine-sim blocks: sim[c][i][j] = clip(<Gn_i, Gn_j>)
__global__ __launch_bounds__(256) void k_sim(const float* __restrict__ Gp, const float* __restrict__ invn,
                                             const int* __restrict__ cnt, const int* __restrict__ off,
                                             float* __restrict__ sim) {
  int c = blockIdx.y;
  int n = min(cnt[c], CAP);
  int ti = blockIdx.x >> 1, tj = blockIdx.x & 1;
  if (ti * 64 >= n || tj * 64 >= n) return;
  int base = off[c];
  __shared__ float As[16][68];
  __shared__ float Bs[16][68];
  const int tx = threadIdx.x & 15, ty = threadIdx.x >> 4;
  const int lr = threadIdx.x >> 2, lq = threadIdx.x & 3;
  float acc[4][4] = {};
  int ra = ti * 64 + lr, rb = tj * 64 + lr;
  bool oka = ra < n, okb = rb < n;
  size_t ga = (size_t)(base + (oka ? ra : 0)) * DIM;
  size_t gb = (size_t)(base + (okb ? rb : 0)) * DIM;
  float sa = oka ? invn[base + ra] : 0.f;
  float sb = okb ? invn[base + rb] : 0.f;
  for (int k0 = 0; k0 < DIM; k0 += 16) {
    float4 va = *(const float4*)(Gp + ga + k0 + lq * 4);
    float4 vb = *(const float4*)(Gp + gb + k0 + lq * 4);
    __syncthreads();
    As[lq * 4 + 0][lr] = va.x * sa; As[lq * 4 + 1][lr] = va.y * sa;
    As[lq * 4 + 2][lr] = va.z * sa; As[lq * 4 + 3][lr] = va.w * sa;
    Bs[lq * 4 + 0][lr] = vb.x * sb; Bs[lq * 4 + 1][lr] = vb.y * sb;
    Bs[lq * 4 + 2][lr] = vb.z * sb; Bs[lq * 4 + 3][lr] = vb.w * sb;
    __syncthreads();
#pragma unroll
    for (int kk = 0; kk < 16; ++kk) {
      float4 a4 = *(const float4*)&As[kk][ty * 4];
      float4 b4 = *(const float4*)&Bs[kk][tx * 4];
      float a[4] = {a4.x, a4.y, a4.z, a4.w}, b[4] = {b4.x, b4.y, b4.z, b4.w};
#pragma unroll
      for (int i = 0; i < 4; ++i)
#pragma unroll
        for (int j = 0; j < 4; ++j) acc[i][j] += a[i] * b[j];
    }
  }
#pragma unroll
  for (int i = 0; i < 4; ++i) {
    int gi = ti * 64 + ty * 4 + i;
    if (gi >= n) continue;
#pragma unroll
    for (int j = 0; j < 4; ++j) {
      int gj = tj * 64 + tx * 4 + j;
      if (gj >= n) continue;
      float v = acc[i][j];
      v = fminf(fmaxf(v, -1.0f + 1e-8f), 1.0f - 1e-8f);
      sim[((size_t)c * CAP + gi) * CAP + gj] = v;
    }
  }
}

// top-8 per row within class (strict-greater insertion == JAX lower-index tiebreak)
__global__ void k_topk(const float* __restrict__ sim, const int* __restrict__ cnt, const int* __restrict__ off,
                       const int* __restrict__ clsp, int* __restrict__ t8) {
  int pr = blockIdx.x * blockDim.x + threadIdx.x;
  if (pr >= NROWS) return;
  int c = clsp[pr];
  int n = min(cnt[c], CAP);
  int loc = pr - off[c];
  const float* row = sim + ((size_t)c * CAP + loc) * CAP;
  float bv[8]; int bi[8];
#pragma unroll
  for (int q = 0; q < 8; ++q) { bv[q] = -3e38f; bi[q] = -1; }
  for (int j = 0; j < n; ++j) {
    if (j == loc) continue;
    float v = row[j];
    if (v > bv[7]) {
      bv[7] = v; bi[7] = j;
#pragma unroll
      for (int q = 7; q > 0; --q) {
        if (bv[q] > bv[q - 1]) {
          float tv = bv[q]; bv[q] = bv[q - 1]; bv[q - 1] = tv;
          int tq = bi[q]; bi[q] = bi[q - 1]; bi[q - 1] = tq;
        }
      }
    }
  }
#pragma unroll
  for (int q = 0; q < 8; ++q) t8[pr * 8 + q] = bi[q];
}

// build normalized graph S (=K) per class block
__global__ __launch_bounds__(256) void k_buildS(const float* __restrict__ sim, const int* __restrict__ cnt,
                                                const int* __restrict__ off, const int* __restrict__ t8,
                                                float alpha, float* __restrict__ S) {
  int c = blockIdx.x;
  int n = min(cnt[c], CAP);
  int base = off[c];
  __shared__ int sh8[CAP * 8];
  __shared__ float dinv[CAP];
  int t = threadIdx.x;
  for (int i = t; i < n * 8; i += 256) sh8[i] = t8[base * 8 + i];
  __syncthreads();
  for (int p = t; p < n * n; p += 256) {
    int i = p / n, j = p % n;
    float w;
    if (i == j) w = 1e-6f;
    else {
      bool m = false;
#pragma unroll
      for (int q = 0; q < 8; ++q) m = m || (sh8[i * 8 + q] == j) || (sh8[j * 8 + q] == i);
      float sv = sim[((size_t)c * CAP + i) * CAP + j];
      w = m ? alpha * fmaxf(sv, 0.f) : 0.f;
    }
    S[((size_t)c * CAP + i) * CAP + j] = w;
  }
  __syncthreads();
  for (int i = t; i < n; i += 256) {
    float d = 0.f;
    const float* r = S + ((size_t)c * CAP + i) * CAP;
    for (int j = 0; j < n; ++j) d += r[j];
    dinv[i] = 1.f / sqrtf(fmaxf(d, 1e-8f));
  }
  __syncthreads();
  for (int p = t; p < n * n; p += 256) {
    int i = p / n, j = p % n;
    S[((size_t)c * CAP + i) * CAP + j] *= dinv[i] * dinv[j];
  }
}

// C[M x ncols] = A[M x 512] @ B[ncols x 512]^T   (64x64 tiles, fp32)
__global__ __launch_bounds__(256) void k_gemm(const float* __restrict__ A, const float* __restrict__ B,
                                              float* __restrict__ C, int ncols) {
  __shared__ float As[16][68];
  __shared__ float Bs[16][68];
  const int row0 = blockIdx.x * 64, col0 = blockIdx.y * 64;
  const int tx = threadIdx.x & 15, ty = threadIdx.x >> 4;
  const int lr = threadIdx.x >> 2, lq = threadIdx.x & 3;
  float acc[4][4] = {};
  const float* pa = A + (size_t)(row0 + lr) * DIM + lq * 4;
  const float* pb = B + (size_t)(col0 + lr) * DIM + lq * 4;
  for (int k0 = 0; k0 < DIM; k0 += 16) {
    float4 va = *(const float4*)(pa + k0);
    float4 vb = *(const float4*)(pb + k0);
    __syncthreads();
    As[lq * 4 + 0][lr] = va.x; As[lq * 4 + 1][lr] = va.y;
    As[lq * 4 + 2][lr] = va.z; As[lq * 4 + 3][lr] = va.w;
    Bs[lq * 4 + 0][lr] = vb.x; Bs[lq * 4 + 1][lr] = vb.y;
    Bs[lq * 4 + 2][lr] = vb.z; Bs[lq * 4 + 3][lr] = vb.w;
    __syncthreads();
#pragma unroll
    for (int kk = 0; kk < 16; ++kk) {
      float4 a4 = *(const float4*)&As[kk][ty * 4];
      float4 b4 = *(const float4*)&Bs[kk][tx * 4];
      float a[4] = {a4.x, a4.y, a4.z, a4.w}, b[4] = {b4.x, b4.y, b4.z, b4.w};
#pragma unroll
      for (int i = 0; i < 4; ++i)
#pragma unroll
        for (int j = 0; j < 4; ++j) acc[i][j] += a[i] * b[j];
    }
  }
#pragma unroll
  for (int i = 0; i < 4; ++i) {
    float4 o = make_float4(acc[i][0], acc[i][1], acc[i][2], acc[i][3]);
    *(float4*)&C[(size_t)(row0 + ty * 4 + i) * ncols + col0 + tx * 4] = o;
  }
}

// Y[base+i][:] = sum_j S[c][i][j] * X[base+j][:]  (+ optional Gadd)
__global__ __launch_bounds__(256) void k_spmm(const float* __restrict__ S, const float* __restrict__ X,
                                              const float* __restrict__ Gadd, float* __restrict__ Y,
                                              const int* __restrict__ cnt, const int* __restrict__ off) {
  int c = blockIdx.x;
  int n = min(cnt[c], CAP);
  int base = off[c];
  int col = blockIdx.y * 256 + threadIdx.x;
  __shared__ float sS[8][CAP];
  for (int i0 = 0; i0 < n; i0 += 8) {
    int ni = min(8, n - i0);
    __syncthreads();
    for (int idx = threadIdx.x; idx < ni * n; idx += 256)
      sS[idx / n][idx % n] = S[((size_t)c * CAP + i0 + idx / n) * CAP + (idx % n)];
    __syncthreads();
    float acc[8] = {0, 0, 0, 0, 0, 0, 0, 0};
    for (int j = 0; j < n; ++j) {
      float x = X[(size_t)(base + j) * DIM + col];
#pragma unroll
      for (int ii = 0; ii < 8; ++ii) acc[ii] += sS[ii][j] * x;
    }
#pragma unroll
    for (int ii = 0; ii < 8; ++ii) {
      if (ii < ni) {
        size_t o = (size_t)(base + i0 + ii) * DIM + col;
        float v = acc[ii];
        if (Gadd) v += Gadd[o];
        Y[o] = v;
      }
    }
  }
}

// column sums / sumsq (64 rows per block)
__global__ __launch_bounds__(256) void k_colstats(const float* __restrict__ X, float* __restrict__ sums) {
  int rb = blockIdx.x, t = threadIdx.x;
#pragma unroll
  for (int cp = 0; cp < 2; ++cp) {
    int col = cp * 256 + t;
    float s = 0.f, s2 = 0.f;
    for (int r = 0; r < 64; ++r) {
      float v = X[(size_t)(rb * 64 + r) * DIM + col];
      s += v; s2 += v * v;
    }
    atomicAdd(&sums[col], s);
    atomicAdd(&sums[DIM + col], s2);
  }
}

__global__ void k_bnfin(const float* __restrict__ sums, const float* __restrict__ gamma,
                        const float* __restrict__ beta, float* __restrict__ sc) {
  int k = blockIdx.x * blockDim.x + threadIdx.x;
  if (k >= DIM) return;
  float m = sums[k] * (1.f / NROWS);
  float var = sums[DIM + k] * (1.f / NROWS) - m * m;
  float s = gamma[k] / sqrtf(var + 1e-5f);
  sc[k] = s;
  sc[DIM + k] = beta[k] - m * s;
}

__global__ __launch_bounds__(256) void k_bnrelu(const float4* __restrict__ X, const float* __restrict__ sc,
                                                float4* __restrict__ Y) {
  int i = blockIdx.x * blockDim.x + threadIdx.x;  // over N*DIM/4
  int cb = (i * 4) & (DIM - 1);
  float4 v = X[i];
  v.x = fmaxf(v.x * sc[cb + 0] + sc[DIM + cb + 0], 0.f);
  v.y = fmaxf(v.y * sc[cb + 1] + sc[DIM + cb + 1], 0.f);
  v.z = fmaxf(v.z * sc[cb + 2] + sc[DIM + cb + 2], 0.f);
  v.w = fmaxf(v.w * sc[cb + 3] + sc[DIM + cb + 3], 0.f);
  Y[i] = v;
}

__global__ __launch_bounds__(192) void k_rownormP(float* __restrict__ P) {
  __shared__ float red[3];
  __shared__ float s_inv;
  int row = blockIdx.x, t = threadIdx.x;
  float4* p = (float4*)(P + (size_t)row * PD);
  float4 v = p[t];
  float ss = v.x * v.x + v.y * v.y + v.z * v.z + v.w * v.w;
  ss = waveReduce(ss);
  if ((t & 63) == 0) red[t >> 6] = ss;
  __syncthreads();
  if (t == 0) s_inv = 1.f / fmaxf(sqrtf(red[0] + red[1] + red[2]), 1e-12f);
  __syncthreads();
  float inv = s_inv;
  v.x *= inv; v.y *= inv; v.z *= inv; v.w *= inv;
  p[t] = v;
}

__global__ __launch_bounds__(256) void k_lossdiff(const float* __restrict__ A, const float* __restrict__ B,
                                                  int n, float coef, float* __restrict__ acc) {
  float s = 0.f;
  for (int i = blockIdx.x * blockDim.x + threadIdx.x; i < n; i += gridDim.x * blockDim.x) {
    float d = A[i] - B[i];
    s += d * d;
  }
  s = blockReduce(s);
  if (threadIdx.x == 0) atomicAdd(acc, s * coef);
}

// per-class block loss: (Sa - Sb)^2 or (Sa - target)^2
__global__ __launch_bounds__(256) void k_lossS(const float* __restrict__ Sa, const float* __restrict__ Sb,
                                               const int* __restrict__ cnt, float target, float coef,
                                               float* __restrict__ acc) {
  int c = blockIdx.x;
  int n = min(cnt[c], CAP);
  float s = 0.f;
  for (int p = threadIdx.x; p < n * n; p += 256) {
    int i = p / n, j = p % n;
    size_t o = ((size_t)c * CAP + i) * CAP + j;
    float d = Sb ? (Sa[o] - Sb[o]) : (Sa[o] - target);
    s += d * d;
  }
  s = blockReduce(s);
  if (threadIdx.x == 0) atomicAdd(acc, s * coef);
}

__global__ void k_final(const float* __restrict__ acc, float* __restrict__ out) {
  if (threadIdx.x == 0) out[0] = acc[0];
}

// ---------------- host ----------------
extern "C" void kernel_launch(void* const* d_in, const int* in_sizes, int n_in,
                              void* d_out, int out_size, void* d_ws, size_t ws_size,
                              hipStream_t stream) {
  const float* feats = (const float*)d_in[0];
  const int* labels = (const int*)d_in[1];
  const float* fc1 = (const float*)d_in[2];
  const float* fc2 = (const float*)d_in[3];
  const float* gamma = (const float*)d_in[4];
  const float* beta = (const float*)d_in[5];
  const float* proj = (const float*)d_in[6];
  float* out = (float*)d_out;

  char* w = (char*)d_ws;
  auto alloc = [&](size_t bytes) { char* p = w; w += (bytes + 255) & ~(size_t)255; return p; };
  float* Gp   = (float*)alloc((size_t)NROWS * DIM * 4);
  float* bufA = (float*)alloc((size_t)NROWS * DIM * 4);
  float* bufB = (float*)alloc((size_t)NROWS * DIM * 4);
  float* sim  = (float*)alloc((size_t)NCLS * CAP * CAP * 4);
  float* S0   = (float*)alloc((size_t)NCLS * CAP * CAP * 4);
  float* S1   = (float*)alloc((size_t)NCLS * CAP * CAP * 4);
  float* PA   = (float*)alloc((size_t)NROWS * PD * 4);
  float* PB   = (float*)alloc((size_t)NROWS * PD * 4);
  float* invn = (float*)alloc(NROWS * 4);
  float* bns  = (float*)alloc(2 * DIM * 4);
  float* bnsc = (float*)alloc(2 * DIM * 4);
  float* acc  = (float*)alloc(256);
  int* cnt  = (int*)alloc(NCLS * 4);
  int* offc = (int*)alloc((NCLS + 1) * 4);
  int* perm = (int*)alloc(NROWS * 4);
  int* clsp = (int*)alloc(NROWS * 4);
  int* t8   = (int*)alloc(NROWS * 8 * 4);

  const float LAM_K = 64.f, LAM_Z = 16.f, SIGMA = 0.99f;
  const float cK = LAM_K / ((float)NROWS * (float)NROWS);
  const float cZ = LAM_Z / ((float)NROWS * (float)PD);
  const float cI = 1.f / ((float)NROWS * (float)NROWS);

  hipLaunchKernelGGL(k_zerof, dim3(1), dim3(64), 0, stream, acc, 4);
  hipLaunchKernelGGL(k_bucket, dim3(1), dim3(64), 0, stream, labels, cnt, offc, perm, clsp);

  float* Sbuf[2] = {S0, S1};
  float* Pbuf[2] = {PA, PB};

  for (int l = 0; l < 3; ++l) {
    const float* G = feats + (size_t)l * NROWS * DIM;
    float alpha = 1.0f + 0.1f * l;
    float* Scur = Sbuf[l & 1];
    float* Sprev = Sbuf[(l & 1) ^ 1];
    float* Pcur = Pbuf[l & 1];
    float* Pprev = Pbuf[(l & 1) ^ 1];

    hipLaunchKernelGGL(k_gather, dim3(NROWS), dim3(128), 0, stream, G, perm, Gp, invn);
    hipLaunchKernelGGL(k_sim, dim3(4, NCLS), dim3(256), 0, stream, Gp, invn, cnt, offc, sim);
    hipLaunchKernelGGL(k_topk, dim3(16), dim3(256), 0, stream, sim, cnt, offc, clsp, t8);
    hipLaunchKernelGGL(k_buildS, dim3(NCLS), dim3(256), 0, stream, sim, cnt, offc, t8, alpha, Scur);

    // T1 = Gp @ w1^T
    hipLaunchKernelGGL(k_gemm, dim3(NROWS / 64, DIM / 64), dim3(256), 0, stream,
                       Gp, fc1 + (size_t)l * DIM * DIM, bufA, DIM);
    // T2 = S @ T1
    hipLaunchKernelGGL(k_spmm, dim3(NCLS, 2), dim3(256), 0, stream, Scur, bufA, (const float*)nullptr, bufB, cnt, offc);
    // BN stats + relu
    hipLaunchKernelGGL(k_zerof, dim3(1), dim3(256), 0, stream, bns, 2 * DIM);
    hipLaunchKernelGGL(k_colstats, dim3(NROWS / 64), dim3(256), 0, stream, bufB, bns);
    hipLaunchKernelGGL(k_bnfin, dim3(2), dim3(256), 0, stream, bns, gamma + (size_t)l * DIM, beta + (size_t)l * DIM, bnsc);
    hipLaunchKernelGGL(k_bnrelu, dim3(NROWS * DIM / 4 / 256), dim3(256), 0, stream,
                       (const float4*)bufB, bnsc, (float4*)bufA);
    // T4 = T3 @ w2^T
    hipLaunchKernelGGL(k_gemm, dim3(NROWS / 64, DIM / 64), dim3(256), 0, stream,
                       bufA, fc2 + (size_t)l * DIM * DIM, bufB, DIM);
    // Z = S @ T4 + Gp
    hipLaunchKernelGGL(k_spmm, dim3(NCLS, 2), dim3(256), 0, stream, Scur, bufB, Gp, bufA, cnt, offc);
    // P = l2norm(Z @ proj^T)
    hipLaunchKernelGGL(k_gemm, dim3(NROWS / 64, PD / 64), dim3(256), 0, stream, bufA, proj, Pcur, PD);
    hipLaunchKernelGGL(k_rownormP, dim3(NROWS), dim3(192), 0, stream, Pcur);

    if (l >= 1) {
      hipLaunchKernelGGL(k_lossS, dim3(NCLS), dim3(256), 0, stream, Sprev, Scur, cnt, 0.f, cK, acc);
      hipLaunchKernelGGL(k_lossdiff, dim3(1024), dim3(256), 0, stream, Pprev, Pcur, NROWS * PD, cZ, acc);
    }
    if (l == 2) {
      hipLaunchKernelGGL(k_lossS, dim3(NCLS), dim3(256), 0, stream, Scur, (const float*)nullptr, cnt, SIGMA, cI, acc);
    }
  }
  hipLaunchKernelGGL(k_final, dim3(1), dim3(64), 0, stream, acc, out);
}

// Round 2
// 1042.535 us; speedup vs baseline: 1.5016x; 1.5016x over previous
//
#include <hip/hip_runtime.h>
#include <math.h>

#define NROWS 4096
#define DIM   512
#define NCLS  64
#define CAP   128
#define PD    768

typedef __attribute__((ext_vector_type(8))) short short8v;
typedef __attribute__((ext_vector_type(4))) float f32x4;

__device__ __forceinline__ unsigned short f2bf(float f) {
  unsigned u = __float_as_uint(f);
  unsigned r = (u + 0x7FFF + ((u >> 16) & 1)) >> 16;
  return (unsigned short)r;
}

// ---------------- reduction helpers ----------------
__device__ __forceinline__ float waveReduce(float v) {
#pragma unroll
  for (int o = 32; o > 0; o >>= 1) v += __shfl_down(v, o);
  return v;
}

__device__ __forceinline__ float blockReduce(float v) {
  __shared__ float sh[4];
  int lane = threadIdx.x & 63, wv = threadIdx.x >> 6;
  v = waveReduce(v);
  if (lane == 0) sh[wv] = v;
  __syncthreads();
  float t = 0.f;
  if (threadIdx.x == 0) {
    int nw = (blockDim.x + 63) >> 6;
    for (int i = 0; i < nw; ++i) t += sh[i];
  }
  return t;
}

// ---------------- misc ----------------
__global__ void k_zerof(float* p, int n) {
  for (int i = blockIdx.x * blockDim.x + threadIdx.x; i < n; i += gridDim.x * blockDim.x) p[i] = 0.f;
}

// ---------------- parallel stable bucketing ----------------
__global__ __launch_bounds__(256) void k_hist(const int* __restrict__ labels, int* __restrict__ chunkCnt) {
  __shared__ int h[NCLS];
  int t = threadIdx.x;
  if (t < NCLS) h[t] = 0;
  __syncthreads();
  atomicAdd(&h[labels[blockIdx.x * 256 + t]], 1);
  __syncthreads();
  if (t < NCLS) chunkCnt[blockIdx.x * NCLS + t] = h[t];
}

__global__ void k_scan(const int* __restrict__ chunkCnt, int* __restrict__ cnt,
                       int* __restrict__ off, int* __restrict__ chunkBase) {
  __shared__ int sc[NCLS];
  int c = threadIdx.x;  // 64 threads
  int tot = 0;
  for (int b = 0; b < 16; ++b) tot += chunkCnt[b * NCLS + c];
  cnt[c] = tot;
  sc[c] = tot;
  __syncthreads();
  if (c == 0) {
    int s = 0;
    for (int i = 0; i < NCLS; ++i) { int tv = sc[i]; sc[i] = s; s += tv; }
  }
  __syncthreads();
  int run = sc[c];
  off[c] = run;
  for (int b = 0; b < 16; ++b) { chunkBase[b * NCLS + c] = run; run += chunkCnt[b * NCLS + c]; }
  if (c == 0) off[NCLS] = NROWS;
}

__global__ __launch_bounds__(256) void k_scatter(const int* __restrict__ labels, const int* __restrict__ chunkBase,
                                                 int* __restrict__ perm, int* __restrict__ clsp) {
  __shared__ int lab[256];
  int t = threadIdx.x;
  int r = blockIdx.x * 256 + t;
  int c = labels[r];
  lab[t] = c;
  __syncthreads();
  int rank = 0;
  for (int j = 0; j < t; ++j) rank += (lab[j] == c);
  int pos = chunkBase[blockIdx.x * NCLS + c] + rank;
  perm[pos] = r;
  clsp[pos] = c;
}

// gathered bf16 copy + row inverse norms (fp32)
__global__ __launch_bounds__(128) void k_prep(const float* __restrict__ G, const int* __restrict__ perm,
                                              unsigned short* __restrict__ Gpb, float* __restrict__ invn) {
  __shared__ float red[2];
  int row = blockIdx.x, t = threadIdx.x;
  const float4* src = (const float4*)(G + (size_t)perm[row] * DIM);
  float4 v = src[t];
  ushort4 b;
  b.x = f2bf(v.x); b.y = f2bf(v.y); b.z = f2bf(v.z); b.w = f2bf(v.w);
  *(ushort4*)(Gpb + (size_t)row * DIM + t * 4) = b;
  float ss = v.x * v.x + v.y * v.y + v.z * v.z + v.w * v.w;
  ss = waveReduce(ss);
  if ((t & 63) == 0) red[t >> 6] = ss;
  __syncthreads();
  if (t == 0) invn[row] = 1.f / fmaxf(sqrtf(red[0] + red[1]), 1e-12f);
}

__global__ void k_tobf16(const float4* __restrict__ src, ushort4* __restrict__ dst, int n4) {
  int i = blockIdx.x * blockDim.x + threadIdx.x;
  if (i < n4) {
    float4 v = src[i];
    ushort4 o;
    o.x = f2bf(v.x); o.y = f2bf(v.y); o.z = f2bf(v.z); o.w = f2bf(v.w);
    dst[i] = o;
  }
}

// per-class cosine-sim blocks (fp32 exact), reading feats via perm
__global__ __launch_bounds__(256) void k_sim(const float* __restrict__ G, const int* __restrict__ perm,
                                             const float* __restrict__ invn,
                                             const int* __restrict__ cnt, const int* __restrict__ off,
                                             float* __restrict__ sim) {
  int c = blockIdx.y;
  int n = min(cnt[c], CAP);
  int ti = blockIdx.x >> 1, tj = blockIdx.x & 1;
  if (ti * 64 >= n || tj * 64 >= n) return;
  int base = off[c];
  __shared__ float As[16][68];
  __shared__ float Bs[16][68];
  const int tx = threadIdx.x & 15, ty = threadIdx.x >> 4;
  const int lr = threadIdx.x >> 2, lq = threadIdx.x & 3;
  float acc[4][4] = {};
  int ra = ti * 64 + lr, rb = tj * 64 + lr;
  bool oka = ra < n, okb = rb < n;
  size_t ga = (size_t)perm[base + (oka ? ra : 0)] * DIM;
  size_t gb = (size_t)perm[base + (okb ? rb : 0)] * DIM;
  float sa = oka ? invn[base + ra] : 0.f;
  float sb = okb ? invn[base + rb] : 0.f;
  for (int k0 = 0; k0 < DIM; k0 += 16) {
    float4 va = *(const float4*)(G + ga + k0 + lq * 4);
    float4 vb = *(const float4*)(G + gb + k0 + lq * 4);
    __syncthreads();
    As[lq * 4 + 0][lr] = va.x * sa; As[lq * 4 + 1][lr] = va.y * sa;
    As[lq * 4 + 2][lr] = va.z * sa; As[lq * 4 + 3][lr] = va.w * sa;
    Bs[lq * 4 + 0][lr] = vb.x * sb; Bs[lq * 4 + 1][lr] = vb.y * sb;
    Bs[lq * 4 + 2][lr] = vb.z * sb; Bs[lq * 4 + 3][lr] = vb.w * sb;
    __syncthreads();
#pragma unroll
    for (int kk = 0; kk < 16; ++kk) {
      float4 a4 = *(const float4*)&As[kk][ty * 4];
      float4 b4 = *(const float4*)&Bs[kk][tx * 4];
      float a[4] = {a4.x, a4.y, a4.z, a4.w}, b[4] = {b4.x, b4.y, b4.z, b4.w};
#pragma unroll
      for (int i = 0; i < 4; ++i)
#pragma unroll
        for (int j = 0; j < 4; ++j) acc[i][j] += a[i] * b[j];
    }
  }
#pragma unroll
  for (int i = 0; i < 4; ++i) {
    int gi = ti * 64 + ty * 4 + i;
    if (gi >= n) continue;
#pragma unroll
    for (int j = 0; j < 4; ++j) {
      int gj = tj * 64 + tx * 4 + j;
      if (gj >= n) continue;
      float v = acc[i][j];
      v = fminf(fmaxf(v, -1.0f + 1e-8f), 1.0f - 1e-8f);
      sim[((size_t)c * CAP + gi) * CAP + gj] = v;
    }
  }
}

// top-8 per row within class
__global__ void k_topk(const float* __restrict__ sim, const int* __restrict__ cnt, const int* __restrict__ off,
                       const int* __restrict__ clsp, int* __restrict__ t8) {
  int pr = blockIdx.x * blockDim.x + threadIdx.x;
  if (pr >= NROWS) return;
  int c = clsp[pr];
  int n = min(cnt[c], CAP);
  int loc = pr - off[c];
  const float* row = sim + ((size_t)c * CAP + loc) * CAP;
  float bv[8]; int bi[8];
#pragma unroll
  for (int q = 0; q < 8; ++q) { bv[q] = -3e38f; bi[q] = -1; }
  for (int j = 0; j < n; ++j) {
    if (j == loc) continue;
    float v = row[j];
    if (v > bv[7]) {
      bv[7] = v; bi[7] = j;
#pragma unroll
      for (int q = 7; q > 0; --q) {
        if (bv[q] > bv[q - 1]) {
          float tv = bv[q]; bv[q] = bv[q - 1]; bv[q - 1] = tv;
          int tq = bi[q]; bi[q] = bi[q - 1]; bi[q - 1] = tq;
        }
      }
    }
  }
#pragma unroll
  for (int q = 0; q < 8; ++q) t8[pr * 8 + q] = bi[q];
}

// build normalized graph S per class block
__global__ __launch_bounds__(256) void k_buildS(const float* __restrict__ sim, const int* __restrict__ cnt,
                                                const int* __restrict__ off, const int* __restrict__ t8,
                                                float alpha, float* __restrict__ S) {
  int c = blockIdx.x;
  int n = min(cnt[c], CAP);
  int base = off[c];
  __shared__ int sh8[CAP * 8];
  __shared__ float dinv[CAP];
  int t = threadIdx.x;
  for (int i = t; i < n * 8; i += 256) sh8[i] = t8[base * 8 + i];
  __syncthreads();
  for (int p = t; p < n * n; p += 256) {
    int i = p / n, j = p % n;
    float w;
    if (i == j) w = 1e-6f;
    else {
      bool m = false;
#pragma unroll
      for (int q = 0; q < 8; ++q) m = m || (sh8[i * 8 + q] == j) || (sh8[j * 8 + q] == i);
      float sv = sim[((size_t)c * CAP + i) * CAP + j];
      w = m ? alpha * fmaxf(sv, 0.f) : 0.f;
    }
    S[((size_t)c * CAP + i) * CAP + j] = w;
  }
  __syncthreads();
  for (int i = t; i < n; i += 256) {
    float d = 0.f;
    const float* r = S + ((size_t)c * CAP + i) * CAP;
    for (int j = 0; j < n; ++j) d += r[j];
    dinv[i] = 1.f / sqrtf(fmaxf(d, 1e-8f));
  }
  __syncthreads();
  for (int p = t; p < n * n; p += 256) {
    int i = p / n, j = p % n;
    S[((size_t)c * CAP + i) * CAP + j] *= dinv[i] * dinv[j];
  }
}

// ------------- bf16 MFMA GEMM: C[4096 x N] = A[4096 x 512] @ B[N x 512]^T -------------
__global__ __launch_bounds__(256) void k_gemm_bf16(const short* __restrict__ A, const short* __restrict__ B,
                                                   float* __restrict__ C, int N) {
  __shared__ short As[128][40];
  __shared__ short Bs[128][40];
  const int row0 = blockIdx.x * 128, col0 = blockIdx.y * 128;
  const int t = threadIdx.x;
  const int lane = t & 63, wv = t >> 6;
  const int wm = wv >> 1, wn = wv & 1;
  const int fr = lane & 15, kg = lane >> 4;
  const int srow = t >> 1, sk = (t & 1) * 16;
  const short* pa = A + (size_t)(row0 + srow) * DIM + sk;
  const short* pb = B + (size_t)(col0 + srow) * DIM + sk;
  f32x4 acc[4][4] = {};
  for (int kt = 0; kt < DIM; kt += 32) {
    short8v a0 = *(const short8v*)(pa + kt);
    short8v a1 = *(const short8v*)(pa + kt + 8);
    short8v b0 = *(const short8v*)(pb + kt);
    short8v b1 = *(const short8v*)(pb + kt + 8);
    __syncthreads();
    *(short8v*)&As[srow][sk] = a0;
    *(short8v*)&As[srow][sk + 8] = a1;
    *(short8v*)&Bs[srow][sk] = b0;
    *(short8v*)&Bs[srow][sk + 8] = b1;
    __syncthreads();
    short8v af[4], bf[4];
#pragma unroll
    for (int i = 0; i < 4; ++i) {
      af[i] = *(const short8v*)&As[wm * 64 + i * 16 + fr][kg * 8];
      bf[i] = *(const short8v*)&Bs[wn * 64 + i * 16 + fr][kg * 8];
    }
#pragma unroll
    for (int i = 0; i < 4; ++i)
#pragma unroll
      for (int j = 0; j < 4; ++j)
        acc[i][j] = __builtin_amdgcn_mfma_f32_16x16x32_bf16(af[i], bf[j], acc[i][j], 0, 0, 0);
  }
#pragma unroll
  for (int i = 0; i < 4; ++i) {
    int r0 = row0 + wm * 64 + i * 16 + kg * 4;
#pragma unroll
    for (int j = 0; j < 4; ++j) {
      int cc = col0 + wn * 64 + j * 16 + fr;
#pragma unroll
      for (int r = 0; r < 4; ++r)
        C[(size_t)(r0 + r) * N + cc] = acc[i][j][r];
    }
  }
}

// Y[base+i][:] = sum_j S[c][i][j] * X[base+j][:]  (+ optional residual from feats via perm)
// output fp32 (Y) or bf16 (Yb)
__global__ __launch_bounds__(256) void k_spmm(const float* __restrict__ S, const float* __restrict__ X,
                                              const float* __restrict__ Gfeat, const int* __restrict__ perm,
                                              float* __restrict__ Y, unsigned short* __restrict__ Yb,
                                              const int* __restrict__ cnt, const int* __restrict__ off) {
  int c = blockIdx.x;
  int n = min(cnt[c], CAP);
  int base = off[c];
  int col = blockIdx.y * 256 + threadIdx.x;
  __shared__ float sS[8][CAP];
  for (int i0 = 0; i0 < n; i0 += 8) {
    int ni = min(8, n - i0);
    __syncthreads();
    for (int idx = threadIdx.x; idx < ni * n; idx += 256)
      sS[idx / n][idx % n] = S[((size_t)c * CAP + i0 + idx / n) * CAP + (idx % n)];
    __syncthreads();
    float acc[8] = {0, 0, 0, 0, 0, 0, 0, 0};
    for (int j = 0; j < n; ++j) {
      float x = X[(size_t)(base + j) * DIM + col];
#pragma unroll
      for (int ii = 0; ii < 8; ++ii) acc[ii] += sS[ii][j] * x;
    }
#pragma unroll
    for (int ii = 0; ii < 8; ++ii) {
      if (ii < ni) {
        size_t o = (size_t)(base + i0 + ii) * DIM + col;
        float v = acc[ii];
        if (Gfeat) v += Gfeat[(size_t)perm[base + i0 + ii] * DIM + col];
        if (Yb) Yb[o] = f2bf(v);
        else Y[o] = v;
      }
    }
  }
}

// column sums / sumsq
__global__ __launch_bounds__(256) void k_colstats(const float* __restrict__ X, float* __restrict__ sums) {
  int rb = blockIdx.x, t = threadIdx.x;
#pragma unroll
  for (int cp = 0; cp < 2; ++cp) {
    int col = cp * 256 + t;
    float s = 0.f, s2 = 0.f;
    for (int r = 0; r < 64; ++r) {
      float v = X[(size_t)(rb * 64 + r) * DIM + col];
      s += v; s2 += v * v;
    }
    atomicAdd(&sums[col], s);
    atomicAdd(&sums[DIM + col], s2);
  }
}

__global__ void k_bnfin(const float* __restrict__ sums, const float* __restrict__ gamma,
                        const float* __restrict__ beta, float* __restrict__ sc) {
  int k = blockIdx.x * blockDim.x + threadIdx.x;
  if (k >= DIM) return;
  float m = sums[k] * (1.f / NROWS);
  float var = sums[DIM + k] * (1.f / NROWS) - m * m;
  float s = gamma[k] / sqrtf(var + 1e-5f);
  sc[k] = s;
  sc[DIM + k] = beta[k] - m * s;
}

// BN+ReLU, writes bf16
__global__ __launch_bounds__(256) void k_bnrelu(const float4* __restrict__ X, const float* __restrict__ sc,
                                                ushort4* __restrict__ Yb) {
  int i = blockIdx.x * blockDim.x + threadIdx.x;
  int cb = (i * 4) & (DIM - 1);
  float4 v = X[i];
  ushort4 o;
  o.x = f2bf(fmaxf(v.x * sc[cb + 0] + sc[DIM + cb + 0], 0.f));
  o.y = f2bf(fmaxf(v.y * sc[cb + 1] + sc[DIM + cb + 1], 0.f));
  o.z = f2bf(fmaxf(v.z * sc[cb + 2] + sc[DIM + cb + 2], 0.f));
  o.w = f2bf(fmaxf(v.w * sc[cb + 3] + sc[DIM + cb + 3], 0.f));
  Yb[i] = o;
}

__global__ __launch_bounds__(192) void k_rownormP(float* __restrict__ P) {
  __shared__ float red[3];
  __shared__ float s_inv;
  int row = blockIdx.x, t = threadIdx.x;
  float4* p = (float4*)(P + (size_t)row * PD);
  float4 v = p[t];
  float ss = v.x * v.x + v.y * v.y + v.z * v.z + v.w * v.w;
  ss = waveReduce(ss);
  if ((t & 63) == 0) red[t >> 6] = ss;
  __syncthreads();
  if (t == 0) s_inv = 1.f / fmaxf(sqrtf(red[0] + red[1] + red[2]), 1e-12f);
  __syncthreads();
  float inv = s_inv;
  v.x *= inv; v.y *= inv; v.z *= inv; v.w *= inv;
  p[t] = v;
}

__global__ __launch_bounds__(256) void k_lossdiff(const float* __restrict__ A, const float* __restrict__ B,
                                                  int n, float coef, float* __restrict__ acc) {
  float s = 0.f;
  for (int i = blockIdx.x * blockDim.x + threadIdx.x; i < n; i += gridDim.x * blockDim.x) {
    float d = A[i] - B[i];
    s += d * d;
  }
  s = blockReduce(s);
  if (threadIdx.x == 0) atomicAdd(acc, s * coef);
}

__global__ __launch_bounds__(256) void k_lossS(const float* __restrict__ Sa, const float* __restrict__ Sb,
                                               const int* __restrict__ cnt, float target, float coef,
                                               float* __restrict__ acc) {
  int c = blockIdx.x;
  int n = min(cnt[c], CAP);
  float s = 0.f;
  for (int p = threadIdx.x; p < n * n; p += 256) {
    int i = p / n, j = p % n;
    size_t o = ((size_t)c * CAP + i) * CAP + j;
    float d = Sb ? (Sa[o] - Sb[o]) : (Sa[o] - target);
    s += d * d;
  }
  s = blockReduce(s);
  if (threadIdx.x == 0) atomicAdd(acc, s * coef);
}

__global__ void k_final(const float* __restrict__ acc, float* __restrict__ out) {
  if (threadIdx.x == 0) out[0] = acc[0];
}

// ---------------- host ----------------
extern "C" void kernel_launch(void* const* d_in, const int* in_sizes, int n_in,
                              void* d_out, int out_size, void* d_ws, size_t ws_size,
                              hipStream_t stream) {
  const float* feats = (const float*)d_in[0];
  const int* labels = (const int*)d_in[1];
  const float* fc1 = (const float*)d_in[2];
  const float* fc2 = (const float*)d_in[3];
  const float* gamma = (const float*)d_in[4];
  const float* beta = (const float*)d_in[5];
  const float* proj = (const float*)d_in[6];
  float* out = (float*)d_out;

  char* w = (char*)d_ws;
  auto alloc = [&](size_t bytes) { char* p = w; w += (bytes + 255) & ~(size_t)255; return p; };
  float* bufA = (float*)alloc((size_t)NROWS * DIM * 4);
  float* bufB = (float*)alloc((size_t)NROWS * DIM * 4);
  unsigned short* Gpb = (unsigned short*)alloc((size_t)NROWS * DIM * 2);
  unsigned short* actb = (unsigned short*)alloc((size_t)NROWS * DIM * 2);  // T3b then Zb
  unsigned short* W1b = (unsigned short*)alloc((size_t)DIM * DIM * 2);
  unsigned short* W2b = (unsigned short*)alloc((size_t)DIM * DIM * 2);
  unsigned short* Pjb = (unsigned short*)alloc((size_t)PD * DIM * 2);
  float* sim  = (float*)alloc((size_t)NCLS * CAP * CAP * 4);
  float* S0   = (float*)alloc((size_t)NCLS * CAP * CAP * 4);
  float* S1   = (float*)alloc((size_t)NCLS * CAP * CAP * 4);
  float* PA   = (float*)alloc((size_t)NROWS * PD * 4);
  float* PB   = (float*)alloc((size_t)NROWS * PD * 4);
  float* invn = (float*)alloc(NROWS * 4);
  float* bns  = (float*)alloc(2 * DIM * 4);
  float* bnsc = (float*)alloc(2 * DIM * 4);
  float* acc  = (float*)alloc(256);
  int* cnt  = (int*)alloc(NCLS * 4);
  int* offc = (int*)alloc((NCLS + 1) * 4);
  int* perm = (int*)alloc(NROWS * 4);
  int* clsp = (int*)alloc(NROWS * 4);
  int* t8   = (int*)alloc(NROWS * 8 * 4);
  int* chunkCnt  = (int*)alloc(16 * NCLS * 4);
  int* chunkBase = (int*)alloc(16 * NCLS * 4);

  const float LAM_K = 64.f, LAM_Z = 16.f, SIGMA = 0.99f;
  const float cK = LAM_K / ((float)NROWS * (float)NROWS);
  const float cZ = LAM_Z / ((float)NROWS * (float)PD);
  const float cI = 1.f / ((float)NROWS * (float)NROWS);

  hipLaunchKernelGGL(k_zerof, dim3(1), dim3(64), 0, stream, acc, 4);
  hipLaunchKernelGGL(k_hist, dim3(16), dim3(256), 0, stream, labels, chunkCnt);
  hipLaunchKernelGGL(k_scan, dim3(1), dim3(64), 0, stream, chunkCnt, cnt, offc, chunkBase);
  hipLaunchKernelGGL(k_scatter, dim3(16), dim3(256), 0, stream, labels, chunkBase, perm, clsp);
  hipLaunchKernelGGL(k_tobf16, dim3((PD * DIM / 4 + 255) / 256), dim3(256), 0, stream,
                     (const float4*)proj, (ushort4*)Pjb, PD * DIM / 4);

  float* Sbuf[2] = {S0, S1};
  float* Pbuf[2] = {PA, PB};

  for (int l = 0; l < 3; ++l) {
    const float* G = feats + (size_t)l * NROWS * DIM;
    float alpha = 1.0f + 0.1f * l;
    float* Scur = Sbuf[l & 1];
    float* Sprev = Sbuf[(l & 1) ^ 1];
    float* Pcur = Pbuf[l & 1];
    float* Pprev = Pbuf[(l & 1) ^ 1];

    hipLaunchKernelGGL(k_tobf16, dim3(DIM * DIM / 4 / 256), dim3(256), 0, stream,
                       (const float4*)(fc1 + (size_t)l * DIM * DIM), (ushort4*)W1b, DIM * DIM / 4);
    hipLaunchKernelGGL(k_tobf16, dim3(DIM * DIM / 4 / 256), dim3(256), 0, stream,
                       (const float4*)(fc2 + (size_t)l * DIM * DIM), (ushort4*)W2b, DIM * DIM / 4);

    hipLaunchKernelGGL(k_prep, dim3(NROWS), dim3(128), 0, stream, G, perm, Gpb, invn);
    hipLaunchKernelGGL(k_sim, dim3(4, NCLS), dim3(256), 0, stream, G, perm, invn, cnt, offc, sim);
    hipLaunchKernelGGL(k_topk, dim3(16), dim3(256), 0, stream, sim, cnt, offc, clsp, t8);
    hipLaunchKernelGGL(k_buildS, dim3(NCLS), dim3(256), 0, stream, sim, cnt, offc, t8, alpha, Scur);

    // T1 = Gp @ w1^T  (bf16 MFMA)
    hipLaunchKernelGGL(k_gemm_bf16, dim3(NROWS / 128, DIM / 128), dim3(256), 0, stream,
                       (const short*)Gpb, (const short*)W1b, bufA, DIM);
    // T2 = S @ T1 (fp32)
    hipLaunchKernelGGL(k_spmm, dim3(NCLS, 2), dim3(256), 0, stream, Scur, bufA,
                       (const float*)nullptr, (const int*)nullptr, bufB, (unsigned short*)nullptr, cnt, offc);
    // BN stats + relu -> bf16 T3
    hipLaunchKernelGGL(k_zerof, dim3(1), dim3(256), 0, stream, bns, 2 * DIM);
    hipLaunchKernelGGL(k_colstats, dim3(NROWS / 64), dim3(256), 0, stream, bufB, bns);
    hipLaunchKernelGGL(k_bnfin, dim3(2), dim3(256), 0, stream, bns, gamma + (size_t)l * DIM, beta + (size_t)l * DIM, bnsc);
    hipLaunchKernelGGL(k_bnrelu, dim3(NROWS * DIM / 4 / 256), dim3(256), 0, stream,
                       (const float4*)bufB, bnsc, (ushort4*)actb);
    // T4 = T3 @ w2^T -> bufB
    hipLaunchKernelGGL(k_gemm_bf16, dim3(NROWS / 128, DIM / 128), dim3(256), 0, stream,
                       (const short*)actb, (const short*)W2b, bufB, DIM);
    // Z = S @ T4 + G (residual via perm) -> bf16 Zb (actb)
    hipLaunchKernelGGL(k_spmm, dim3(NCLS, 2), dim3(256), 0, stream, Scur, bufB,
                       G, perm, (float*)nullptr, actb, cnt, offc);
    // P = l2norm(Z @ proj^T)
    hipLaunchKernelGGL(k_gemm_bf16, dim3(NROWS / 128, PD / 128), dim3(256), 0, stream,
                       (const short*)actb, (const short*)Pjb, Pcur, PD);
    hipLaunchKernelGGL(k_rownormP, dim3(NROWS), dim3(192), 0, stream, Pcur);

    if (l >= 1) {
      hipLaunchKernelGGL(k_lossS, dim3(NCLS), dim3(256), 0, stream, Sprev, Scur, cnt, 0.f, cK, acc);
      hipLaunchKernelGGL(k_lossdiff, dim3(1024), dim3(256), 0, stream, Pprev, Pcur, NROWS * PD, cZ, acc);
    }
    if (l == 2) {
      hipLaunchKernelGGL(k_lossS, dim3(NCLS), dim3(256), 0, stream, Scur, (const float*)nullptr, cnt, SIGMA, cI, acc);
    }
  }
  hipLaunchKernelGGL(k_final, dim3(1), dim3(64), 0, stream, acc, out);
}

// Round 3
// 718.073 us; speedup vs baseline: 2.1801x; 1.4519x over previous
//
#include <hip/hip_runtime.h>
#include <math.h>

#define NROWS 4096
#define DIM   512
#define NCLS  64
#define CAP   128
#define PD    768

typedef __attribute__((ext_vector_type(8))) short short8v;
typedef __attribute__((ext_vector_type(4))) float f32x4;

__device__ __forceinline__ unsigned short f2bf(float f) {
  unsigned u = __float_as_uint(f);
  unsigned r = (u + 0x7FFF + ((u >> 16) & 1)) >> 16;
  return (unsigned short)r;
}

// ---------------- reduction helpers ----------------
__device__ __forceinline__ float waveReduce(float v) {
#pragma unroll
  for (int o = 32; o > 0; o >>= 1) v += __shfl_down(v, o);
  return v;
}

__device__ __forceinline__ float blockReduce(float v) {
  __shared__ float sh[4];
  int lane = threadIdx.x & 63, wv = threadIdx.x >> 6;
  v = waveReduce(v);
  if (lane == 0) sh[wv] = v;
  __syncthreads();
  float t = 0.f;
  if (threadIdx.x == 0) {
    int nw = (blockDim.x + 63) >> 6;
    for (int i = 0; i < nw; ++i) t += sh[i];
  }
  return t;
}

// ---------------- misc ----------------
__global__ void k_zerof(float* p, int n) {
  for (int i = blockIdx.x * blockDim.x + threadIdx.x; i < n; i += gridDim.x * blockDim.x) p[i] = 0.f;
}

// ---------------- parallel stable bucketing ----------------
__global__ __launch_bounds__(256) void k_hist(const int* __restrict__ labels, int* __restrict__ chunkCnt) {
  __shared__ int h[NCLS];
  int t = threadIdx.x;
  if (t < NCLS) h[t] = 0;
  __syncthreads();
  atomicAdd(&h[labels[blockIdx.x * 256 + t]], 1);
  __syncthreads();
  if (t < NCLS) chunkCnt[blockIdx.x * NCLS + t] = h[t];
}

__global__ void k_scan(const int* __restrict__ chunkCnt, int* __restrict__ cnt,
                       int* __restrict__ off, int* __restrict__ chunkBase) {
  __shared__ int sc[NCLS];
  int c = threadIdx.x;  // 64 threads
  int tot = 0;
  for (int b = 0; b < 16; ++b) tot += chunkCnt[b * NCLS + c];
  cnt[c] = tot;
  sc[c] = tot;
  __syncthreads();
  if (c == 0) {
    int s = 0;
    for (int i = 0; i < NCLS; ++i) { int tv = sc[i]; sc[i] = s; s += tv; }
  }
  __syncthreads();
  int run = sc[c];
  off[c] = run;
  for (int b = 0; b < 16; ++b) { chunkBase[b * NCLS + c] = run; run += chunkCnt[b * NCLS + c]; }
  if (c == 0) off[NCLS] = NROWS;
}

__global__ __launch_bounds__(256) void k_scatter(const int* __restrict__ labels, const int* __restrict__ chunkBase,
                                                 int* __restrict__ perm, int* __restrict__ clsp) {
  __shared__ int lab[256];
  int t = threadIdx.x;
  int r = blockIdx.x * 256 + t;
  int c = labels[r];
  lab[t] = c;
  __syncthreads();
  int rank = 0;
  for (int j = 0; j < t; ++j) rank += (lab[j] == c);
  int pos = chunkBase[blockIdx.x * NCLS + c] + rank;
  perm[pos] = r;
  clsp[pos] = c;
}

// gathered bf16 copy + row inverse norms (fp32)
__global__ __launch_bounds__(128) void k_prep(const float* __restrict__ G, const int* __restrict__ perm,
                                              unsigned short* __restrict__ Gpb, float* __restrict__ invn) {
  __shared__ float red[2];
  int row = blockIdx.x, t = threadIdx.x;
  const float4* src = (const float4*)(G + (size_t)perm[row] * DIM);
  float4 v = src[t];
  ushort4 b;
  b.x = f2bf(v.x); b.y = f2bf(v.y); b.z = f2bf(v.z); b.w = f2bf(v.w);
  *(ushort4*)(Gpb + (size_t)row * DIM + t * 4) = b;
  float ss = v.x * v.x + v.y * v.y + v.z * v.z + v.w * v.w;
  ss = waveReduce(ss);
  if ((t & 63) == 0) red[t >> 6] = ss;
  __syncthreads();
  if (t == 0) invn[row] = 1.f / fmaxf(sqrtf(red[0] + red[1]), 1e-12f);
}

__global__ void k_tobf16(const float4* __restrict__ src, ushort4* __restrict__ dst, int n4) {
  int i = blockIdx.x * blockDim.x + threadIdx.x;
  if (i < n4) {
    float4 v = src[i];
    ushort4 o;
    o.x = f2bf(v.x); o.y = f2bf(v.y); o.z = f2bf(v.z); o.w = f2bf(v.w);
    dst[i] = o;
  }
}

// per-class cosine-sim: 32x32 tiles (fp32 exact, same k-accumulation order)
__global__ __launch_bounds__(256) void k_sim(const float* __restrict__ G, const int* __restrict__ perm,
                                             const float* __restrict__ invn,
                                             const int* __restrict__ cnt, const int* __restrict__ off,
                                             float* __restrict__ sim) {
  int c = blockIdx.y;
  int n = min(cnt[c], CAP);
  int ti = blockIdx.x >> 2, tj = blockIdx.x & 3;
  if (ti * 32 >= n || tj * 32 >= n) return;
  int base = off[c];
  __shared__ float As[16][36];
  __shared__ float Bs[16][36];
  const int tx = threadIdx.x & 15, ty = threadIdx.x >> 4;
  const int lr = threadIdx.x >> 3, lq = threadIdx.x & 7;   // 32 rows x 8 k-pairs (float2)
  float acc[2][2] = {};
  int ra = ti * 32 + lr, rb = tj * 32 + lr;
  bool oka = ra < n, okb = rb < n;
  size_t ga = (size_t)perm[base + (oka ? ra : 0)] * DIM;
  size_t gb = (size_t)perm[base + (okb ? rb : 0)] * DIM;
  float sa = oka ? invn[base + ra] : 0.f;
  float sb = okb ? invn[base + rb] : 0.f;
  for (int k0 = 0; k0 < DIM; k0 += 16) {
    float2 va = *(const float2*)(G + ga + k0 + lq * 2);
    float2 vb = *(const float2*)(G + gb + k0 + lq * 2);
    __syncthreads();
    As[lq * 2 + 0][lr] = va.x * sa; As[lq * 2 + 1][lr] = va.y * sa;
    Bs[lq * 2 + 0][lr] = vb.x * sb; Bs[lq * 2 + 1][lr] = vb.y * sb;
    __syncthreads();
#pragma unroll
    for (int kk = 0; kk < 16; ++kk) {
      float2 a2 = *(const float2*)&As[kk][ty * 2];
      float2 b2 = *(const float2*)&Bs[kk][tx * 2];
      acc[0][0] += a2.x * b2.x; acc[0][1] += a2.x * b2.y;
      acc[1][0] += a2.y * b2.x; acc[1][1] += a2.y * b2.y;
    }
  }
#pragma unroll
  for (int i = 0; i < 2; ++i) {
    int gi = ti * 32 + ty * 2 + i;
    if (gi >= n) continue;
#pragma unroll
    for (int j = 0; j < 2; ++j) {
      int gj = tj * 32 + tx * 2 + j;
      if (gj >= n) continue;
      float v = acc[i][j];
      v = fminf(fmaxf(v, -1.0f + 1e-8f), 1.0f - 1e-8f);
      sim[((size_t)c * CAP + gi) * CAP + gj] = v;
    }
  }
}

// top-8 per row within class
__global__ __launch_bounds__(64) void k_topk(const float* __restrict__ sim, const int* __restrict__ cnt,
                                             const int* __restrict__ off, const int* __restrict__ clsp,
                                             int* __restrict__ t8) {
  int pr = blockIdx.x * 64 + threadIdx.x;
  if (pr >= NROWS) return;
  int c = clsp[pr];
  int n = min(cnt[c], CAP);
  int loc = pr - off[c];
  const float* row = sim + ((size_t)c * CAP + loc) * CAP;
  float bv[8]; int bi[8];
#pragma unroll
  for (int q = 0; q < 8; ++q) { bv[q] = -3e38f; bi[q] = -1; }
  for (int j = 0; j < n; ++j) {
    if (j == loc) continue;
    float v = row[j];
    if (v > bv[7]) {
      bv[7] = v; bi[7] = j;
#pragma unroll
      for (int q = 7; q > 0; --q) {
        if (bv[q] > bv[q - 1]) {
          float tv = bv[q]; bv[q] = bv[q - 1]; bv[q - 1] = tv;
          int tq = bi[q]; bi[q] = bi[q - 1]; bi[q - 1] = tq;
        }
      }
    }
  }
#pragma unroll
  for (int q = 0; q < 8; ++q) t8[pr * 8 + q] = bi[q];
}

// build normalized graph S per class block
__global__ __launch_bounds__(256) void k_buildS(const float* __restrict__ sim, const int* __restrict__ cnt,
                                                const int* __restrict__ off, const int* __restrict__ t8,
                                                float alpha, float* __restrict__ S) {
  int c = blockIdx.x;
  int n = min(cnt[c], CAP);
  int base = off[c];
  __shared__ int sh8[CAP * 8];
  __shared__ float dinv[CAP];
  int t = threadIdx.x;
  for (int i = t; i < n * 8; i += 256) sh8[i] = t8[base * 8 + i];
  __syncthreads();
  for (int p = t; p < n * n; p += 256) {
    int i = p / n, j = p % n;
    float w;
    if (i == j) w = 1e-6f;
    else {
      bool m = false;
#pragma unroll
      for (int q = 0; q < 8; ++q) m = m || (sh8[i * 8 + q] == j) || (sh8[j * 8 + q] == i);
      float sv = sim[((size_t)c * CAP + i) * CAP + j];
      w = m ? alpha * fmaxf(sv, 0.f) : 0.f;
    }
    S[((size_t)c * CAP + i) * CAP + j] = w;
  }
  __syncthreads();
  for (int i = t; i < n; i += 256) {
    float d = 0.f;
    const float* r = S + ((size_t)c * CAP + i) * CAP;
    for (int j = 0; j < n; ++j) d += r[j];
    dinv[i] = 1.f / sqrtf(fmaxf(d, 1e-8f));
  }
  __syncthreads();
  for (int p = t; p < n * n; p += 256) {
    int i = p / n, j = p % n;
    S[((size_t)c * CAP + i) * CAP + j] *= dinv[i] * dinv[j];
  }
}

// ------------- bf16 MFMA GEMM: C[4096 x N] = A[4096 x 512] @ B[N x 512]^T -------------
// 128x64 tile, 256 threads (4 waves, each 32 rows x 64 cols)
__global__ __launch_bounds__(256) void k_gemm_bf16(const short* __restrict__ A, const short* __restrict__ B,
                                                   float* __restrict__ C, int N) {
  __shared__ short As[128][40];
  __shared__ short Bs[64][40];
  const int row0 = blockIdx.x * 128, col0 = blockIdx.y * 64;
  const int t = threadIdx.x;
  const int lane = t & 63, wv = t >> 6;
  const int fr = lane & 15, kg = lane >> 4;
  const int sra = t >> 1, ska = (t & 1) * 16;
  const int srb = t >> 2, skb = (t & 3) * 8;
  const short* pa = A + (size_t)(row0 + sra) * DIM + ska;
  const short* pb = B + (size_t)(col0 + srb) * DIM + skb;
  f32x4 acc[2][4] = {};
  for (int kt = 0; kt < DIM; kt += 32) {
    short8v a0 = *(const short8v*)(pa + kt);
    short8v a1 = *(const short8v*)(pa + kt + 8);
    short8v b0 = *(const short8v*)(pb + kt);
    __syncthreads();
    *(short8v*)&As[sra][ska] = a0;
    *(short8v*)&As[sra][ska + 8] = a1;
    *(short8v*)&Bs[srb][skb] = b0;
    __syncthreads();
    short8v af[2], bf[4];
#pragma unroll
    for (int i = 0; i < 2; ++i) af[i] = *(const short8v*)&As[wv * 32 + i * 16 + fr][kg * 8];
#pragma unroll
    for (int j = 0; j < 4; ++j) bf[j] = *(const short8v*)&Bs[j * 16 + fr][kg * 8];
#pragma unroll
    for (int i = 0; i < 2; ++i)
#pragma unroll
      for (int j = 0; j < 4; ++j)
        acc[i][j] = __builtin_amdgcn_mfma_f32_16x16x32_bf16(af[i], bf[j], acc[i][j], 0, 0, 0);
  }
#pragma unroll
  for (int i = 0; i < 2; ++i) {
    int r0 = row0 + wv * 32 + i * 16 + kg * 4;
#pragma unroll
    for (int j = 0; j < 4; ++j) {
      int cc = col0 + j * 16 + fr;
#pragma unroll
      for (int r = 0; r < 4; ++r)
        C[(size_t)(r0 + r) * N + cc] = acc[i][j][r];
    }
  }
}

// Y[base+i][:] = sum_j S[c][i][j] * X[base+j][:] (+ optional residual) — 32 rows x 64 cols per block
__global__ __launch_bounds__(256) void k_spmm2(const float* __restrict__ S, const float* __restrict__ X,
                                               const float* __restrict__ Gfeat, const int* __restrict__ perm,
                                               float* __restrict__ Y, unsigned short* __restrict__ Yb,
                                               const int* __restrict__ cnt, const int* __restrict__ off) {
  int c = blockIdx.x;
  int n = min(cnt[c], CAP);
  int i0 = blockIdx.z * 32;
  if (i0 >= n) return;
  int base = off[c];
  int col = blockIdx.y * 64 + (threadIdx.x & 63);
  int ty = threadIdx.x >> 6;  // 4 groups x 8 rows
  __shared__ float sS[32][CAP];
  for (int idx = threadIdx.x; idx < 32 * n; idx += 256) {
    int r = idx / n, j = idx - r * n;
    sS[r][j] = (i0 + r < n) ? S[((size_t)c * CAP + i0 + r) * CAP + j] : 0.f;
  }
  __syncthreads();
  float acc[8] = {0, 0, 0, 0, 0, 0, 0, 0};
  for (int j = 0; j < n; ++j) {
    float x = X[(size_t)(base + j) * DIM + col];
#pragma unroll
    for (int ii = 0; ii < 8; ++ii) acc[ii] += sS[ty * 8 + ii][j] * x;
  }
#pragma unroll
  for (int ii = 0; ii < 8; ++ii) {
    int r = i0 + ty * 8 + ii;
    if (r < n) {
      size_t o = (size_t)(base + r) * DIM + col;
      float v = acc[ii];
      if (Gfeat) v += Gfeat[(size_t)perm[base + r] * DIM + col];
      if (Yb) Yb[o] = f2bf(v);
      else Y[o] = v;
    }
  }
}

// column sums / sumsq (32 rows per block)
__global__ __launch_bounds__(256) void k_colstats(const float* __restrict__ X, float* __restrict__ sums) {
  int rb = blockIdx.x, t = threadIdx.x;
#pragma unroll
  for (int cp = 0; cp < 2; ++cp) {
    int col = cp * 256 + t;
    float s = 0.f, s2 = 0.f;
    for (int r = 0; r < 32; ++r) {
      float v = X[(size_t)(rb * 32 + r) * DIM + col];
      s += v; s2 += v * v;
    }
    atomicAdd(&sums[col], s);
    atomicAdd(&sums[DIM + col], s2);
  }
}

__global__ void k_bnfin(const float* __restrict__ sums, const float* __restrict__ gamma,
                        const float* __restrict__ beta, float* __restrict__ sc) {
  int k = blockIdx.x * blockDim.x + threadIdx.x;
  if (k >= DIM) return;
  float m = sums[k] * (1.f / NROWS);
  float var = sums[DIM + k] * (1.f / NROWS) - m * m;
  float s = gamma[k] / sqrtf(var + 1e-5f);
  sc[k] = s;
  sc[DIM + k] = beta[k] - m * s;
}

// BN+ReLU, writes bf16
__global__ __launch_bounds__(256) void k_bnrelu(const float4* __restrict__ X, const float* __restrict__ sc,
                                                ushort4* __restrict__ Yb) {
  int i = blockIdx.x * blockDim.x + threadIdx.x;
  int cb = (i * 4) & (DIM - 1);
  float4 v = X[i];
  ushort4 o;
  o.x = f2bf(fmaxf(v.x * sc[cb + 0] + sc[DIM + cb + 0], 0.f));
  o.y = f2bf(fmaxf(v.y * sc[cb + 1] + sc[DIM + cb + 1], 0.f));
  o.z = f2bf(fmaxf(v.z * sc[cb + 2] + sc[DIM + cb + 2], 0.f));
  o.w = f2bf(fmaxf(v.w * sc[cb + 3] + sc[DIM + cb + 3], 0.f));
  Yb[i] = o;
}

__global__ __launch_bounds__(192) void k_rownormP(float* __restrict__ P) {
  __shared__ float red[3];
  __shared__ float s_inv;
  int row = blockIdx.x, t = threadIdx.x;
  float4* p = (float4*)(P + (size_t)row * PD);
  float4 v = p[t];
  float ss = v.x * v.x + v.y * v.y + v.z * v.z + v.w * v.w;
  ss = waveReduce(ss);
  if ((t & 63) == 0) red[t >> 6] = ss;
  __syncthreads();
  if (t == 0) s_inv = 1.f / fmaxf(sqrtf(red[0] + red[1] + red[2]), 1e-12f);
  __syncthreads();
  float inv = s_inv;
  v.x *= inv; v.y *= inv; v.z *= inv; v.w *= inv;
  p[t] = v;
}

__global__ __launch_bounds__(256) void k_lossdiff(const float* __restrict__ A, const float* __restrict__ B,
                                                  int n, float coef, float* __restrict__ acc) {
  float s = 0.f;
  for (int i = blockIdx.x * blockDim.x + threadIdx.x; i < n; i += gridDim.x * blockDim.x) {
    float d = A[i] - B[i];
    s += d * d;
  }
  s = blockReduce(s);
  if (threadIdx.x == 0) atomicAdd(acc, s * coef);
}

__global__ __launch_bounds__(256) void k_lossS(const float* __restrict__ Sa, const float* __restrict__ Sb,
                                               const int* __restrict__ cnt, float target, float coef,
                                               float* __restrict__ acc) {
  int c = blockIdx.x;
  int n = min(cnt[c], CAP);
  float s = 0.f;
  for (int p = threadIdx.x; p < n * n; p += 256) {
    int i = p / n, j = p % n;
    size_t o = ((size_t)c * CAP + i) * CAP + j;
    float d = Sb ? (Sa[o] - Sb[o]) : (Sa[o] - target);
    s += d * d;
  }
  s = blockReduce(s);
  if (threadIdx.x == 0) atomicAdd(acc, s * coef);
}

__global__ void k_final(const float* __restrict__ acc, float* __restrict__ out) {
  if (threadIdx.x == 0) out[0] = acc[0];
}

// ---------------- host ----------------
extern "C" void kernel_launch(void* const* d_in, const int* in_sizes, int n_in,
                              void* d_out, int out_size, void* d_ws, size_t ws_size,
                              hipStream_t stream) {
  const float* feats = (const float*)d_in[0];
  const int* labels = (const int*)d_in[1];
  const float* fc1 = (const float*)d_in[2];
  const float* fc2 = (const float*)d_in[3];
  const float* gamma = (const float*)d_in[4];
  const float* beta = (const float*)d_in[5];
  const float* proj = (const float*)d_in[6];
  float* out = (float*)d_out;

  char* w = (char*)d_ws;
  auto alloc = [&](size_t bytes) { char* p = w; w += (bytes + 255) & ~(size_t)255; return p; };
  float* bufA = (float*)alloc((size_t)NROWS * DIM * 4);
  float* bufB = (float*)alloc((size_t)NROWS * DIM * 4);
  unsigned short* Gpb = (unsigned short*)alloc((size_t)NROWS * DIM * 2);
  unsigned short* actb = (unsigned short*)alloc((size_t)NROWS * DIM * 2);
  unsigned short* W1b = (unsigned short*)alloc((size_t)3 * DIM * DIM * 2);
  unsigned short* W2b = (unsigned short*)alloc((size_t)3 * DIM * DIM * 2);
  unsigned short* Pjb = (unsigned short*)alloc((size_t)PD * DIM * 2);
  float* sim  = (float*)alloc((size_t)NCLS * CAP * CAP * 4);
  float* S0   = (float*)alloc((size_t)NCLS * CAP * CAP * 4);
  float* S1   = (float*)alloc((size_t)NCLS * CAP * CAP * 4);
  float* PA   = (float*)alloc((size_t)NROWS * PD * 4);
  float* PB   = (float*)alloc((size_t)NROWS * PD * 4);
  float* invn = (float*)alloc(NROWS * 4);
  float* bns  = (float*)alloc(2 * DIM * 4);
  float* bnsc = (float*)alloc(2 * DIM * 4);
  float* acc  = (float*)alloc(256);
  int* cnt  = (int*)alloc(NCLS * 4);
  int* offc = (int*)alloc((NCLS + 1) * 4);
  int* perm = (int*)alloc(NROWS * 4);
  int* clsp = (int*)alloc(NROWS * 4);
  int* t8   = (int*)alloc(NROWS * 8 * 4);
  int* chunkCnt  = (int*)alloc(16 * NCLS * 4);
  int* chunkBase = (int*)alloc(16 * NCLS * 4);

  const float LAM_K = 64.f, LAM_Z = 16.f, SIGMA = 0.99f;
  const float cK = LAM_K / ((float)NROWS * (float)NROWS);
  const float cZ = LAM_Z / ((float)NROWS * (float)PD);
  const float cI = 1.f / ((float)NROWS * (float)NROWS);

  hipLaunchKernelGGL(k_zerof, dim3(1), dim3(64), 0, stream, acc, 4);
  hipLaunchKernelGGL(k_hist, dim3(16), dim3(256), 0, stream, labels, chunkCnt);
  hipLaunchKernelGGL(k_scan, dim3(1), dim3(64), 0, stream, chunkCnt, cnt, offc, chunkBase);
  hipLaunchKernelGGL(k_scatter, dim3(16), dim3(256), 0, stream, labels, chunkBase, perm, clsp);
  // all weights -> bf16 once
  hipLaunchKernelGGL(k_tobf16, dim3((3 * DIM * DIM / 4 + 255) / 256), dim3(256), 0, stream,
                     (const float4*)fc1, (ushort4*)W1b, 3 * DIM * DIM / 4);
  hipLaunchKernelGGL(k_tobf16, dim3((3 * DIM * DIM / 4 + 255) / 256), dim3(256), 0, stream,
                     (const float4*)fc2, (ushort4*)W2b, 3 * DIM * DIM / 4);
  hipLaunchKernelGGL(k_tobf16, dim3((PD * DIM / 4 + 255) / 256), dim3(256), 0, stream,
                     (const float4*)proj, (ushort4*)Pjb, PD * DIM / 4);

  float* Sbuf[2] = {S0, S1};
  float* Pbuf[2] = {PA, PB};

  for (int l = 0; l < 3; ++l) {
    const float* G = feats + (size_t)l * NROWS * DIM;
    float alpha = 1.0f + 0.1f * l;
    float* Scur = Sbuf[l & 1];
    float* Sprev = Sbuf[(l & 1) ^ 1];
    float* Pcur = Pbuf[l & 1];
    float* Pprev = Pbuf[(l & 1) ^ 1];

    hipLaunchKernelGGL(k_prep, dim3(NROWS), dim3(128), 0, stream, G, perm, Gpb, invn);
    hipLaunchKernelGGL(k_sim, dim3(16, NCLS), dim3(256), 0, stream, G, perm, invn, cnt, offc, sim);
    hipLaunchKernelGGL(k_topk, dim3(NROWS / 64), dim3(64), 0, stream, sim, cnt, offc, clsp, t8);
    hipLaunchKernelGGL(k_buildS, dim3(NCLS), dim3(256), 0, stream, sim, cnt, offc, t8, alpha, Scur);

    // T1 = Gp @ w1^T  (bf16 MFMA)
    hipLaunchKernelGGL(k_gemm_bf16, dim3(NROWS / 128, DIM / 64), dim3(256), 0, stream,
                       (const short*)Gpb, (const short*)(W1b + (size_t)l * DIM * DIM), bufA, DIM);
    // T2 = S @ T1 (fp32)
    hipLaunchKernelGGL(k_spmm2, dim3(NCLS, DIM / 64, CAP / 32), dim3(256), 0, stream, Scur, bufA,
                       (const float*)nullptr, (const int*)nullptr, bufB, (unsigned short*)nullptr, cnt, offc);
    // BN stats + relu -> bf16 T3
    hipLaunchKernelGGL(k_zerof, dim3(1), dim3(256), 0, stream, bns, 2 * DIM);
    hipLaunchKernelGGL(k_colstats, dim3(NROWS / 32), dim3(256), 0, stream, bufB, bns);
    hipLaunchKernelGGL(k_bnfin, dim3(2), dim3(256), 0, stream, bns, gamma + (size_t)l * DIM, beta + (size_t)l * DIM, bnsc);
    hipLaunchKernelGGL(k_bnrelu, dim3(NROWS * DIM / 4 / 256), dim3(256), 0, stream,
                       (const float4*)bufB, bnsc, (ushort4*)actb);
    // T4 = T3 @ w2^T -> bufB
    hipLaunchKernelGGL(k_gemm_bf16, dim3(NROWS / 128, DIM / 64), dim3(256), 0, stream,
                       (const short*)actb, (const short*)(W2b + (size_t)l * DIM * DIM), bufB, DIM);
    // Z = S @ T4 + G (residual via perm) -> bf16 Zb (actb)
    hipLaunchKernelGGL(k_spmm2, dim3(NCLS, DIM / 64, CAP / 32), dim3(256), 0, stream, Scur, bufB,
                       G, perm, (float*)nullptr, actb, cnt, offc);
    // P = l2norm(Z @ proj^T)
    hipLaunchKernelGGL(k_gemm_bf16, dim3(NROWS / 128, PD / 64), dim3(256), 0, stream,
                       (const short*)actb, (const short*)Pjb, Pcur, PD);
    hipLaunchKernelGGL(k_rownormP, dim3(NROWS), dim3(192), 0, stream, Pcur);

    if (l >= 1) {
      hipLaunchKernelGGL(k_lossS, dim3(NCLS), dim3(256), 0, stream, Sprev, Scur, cnt, 0.f, cK, acc);
      hipLaunchKernelGGL(k_lossdiff, dim3(1024), dim3(256), 0, stream, Pprev, Pcur, NROWS * PD, cZ, acc);
    }
    if (l == 2) {
      hipLaunchKernelGGL(k_lossS, dim3(NCLS), dim3(256), 0, stream, Scur, (const float*)nullptr, cnt, SIGMA, cI, acc);
    }
  }
  hipLaunchKernelGGL(k_final, dim3(1), dim3(64), 0, stream, acc, out);
}

// Round 4
// 629.427 us; speedup vs baseline: 2.4872x; 1.1408x over previous
//
#include <hip/hip_runtime.h>
#include <math.h>

#define NROWS 4096
#define DIM   512
#define NCLS  64
#define CAP   128
#define PD    768

typedef __attribute__((ext_vector_type(8))) short short8v;
typedef __attribute__((ext_vector_type(4))) float f32x4;

__device__ __forceinline__ unsigned short f2bf(float f) {
  unsigned u = __float_as_uint(f);
  unsigned r = (u + 0x7FFF + ((u >> 16) & 1)) >> 16;
  return (unsigned short)r;
}

// ---------------- reduction helpers ----------------
__device__ __forceinline__ float waveReduce(float v) {
#pragma unroll
  for (int o = 32; o > 0; o >>= 1) v += __shfl_down(v, o);
  return v;
}

__device__ __forceinline__ float blockReduce(float v) {
  __shared__ float sh[4];
  int lane = threadIdx.x & 63, wv = threadIdx.x >> 6;
  v = waveReduce(v);
  if (lane == 0) sh[wv] = v;
  __syncthreads();
  float t = 0.f;
  if (threadIdx.x == 0) {
    int nw = (blockDim.x + 63) >> 6;
    for (int i = 0; i < nw; ++i) t += sh[i];
  }
  return t;
}

// ---------------- misc ----------------
__global__ void k_zerof(float* p, int n) {
  for (int i = blockIdx.x * blockDim.x + threadIdx.x; i < n; i += gridDim.x * blockDim.x) p[i] = 0.f;
}

// ---------------- parallel stable bucketing ----------------
__global__ __launch_bounds__(256) void k_hist(const int* __restrict__ labels, int* __restrict__ chunkCnt) {
  __shared__ int h[NCLS];
  int t = threadIdx.x;
  if (t < NCLS) h[t] = 0;
  __syncthreads();
  atomicAdd(&h[labels[blockIdx.x * 256 + t]], 1);
  __syncthreads();
  if (t < NCLS) chunkCnt[blockIdx.x * NCLS + t] = h[t];
}

__global__ void k_scan(const int* __restrict__ chunkCnt, int* __restrict__ cnt,
                       int* __restrict__ off, int* __restrict__ chunkBase) {
  __shared__ int sc[NCLS];
  int c = threadIdx.x;  // 64 threads
  int tot = 0;
  for (int b = 0; b < 16; ++b) tot += chunkCnt[b * NCLS + c];
  cnt[c] = tot;
  sc[c] = tot;
  __syncthreads();
  if (c == 0) {
    int s = 0;
    for (int i = 0; i < NCLS; ++i) { int tv = sc[i]; sc[i] = s; s += tv; }
  }
  __syncthreads();
  int run = sc[c];
  off[c] = run;
  for (int b = 0; b < 16; ++b) { chunkBase[b * NCLS + c] = run; run += chunkCnt[b * NCLS + c]; }
  if (c == 0) off[NCLS] = NROWS;
}

__global__ __launch_bounds__(256) void k_scatter(const int* __restrict__ labels, const int* __restrict__ chunkBase,
                                                 int* __restrict__ perm, int* __restrict__ clsp) {
  __shared__ int lab[256];
  int t = threadIdx.x;
  int r = blockIdx.x * 256 + t;
  int c = labels[r];
  lab[t] = c;
  __syncthreads();
  int rank = 0;
  for (int j = 0; j < t; ++j) rank += (lab[j] == c);
  int pos = chunkBase[blockIdx.x * NCLS + c] + rank;
  perm[pos] = r;
  clsp[pos] = c;
}

// gathered bf16 copy + row inverse norms (fp32)
__global__ __launch_bounds__(128) void k_prep(const float* __restrict__ G, const int* __restrict__ perm,
                                              unsigned short* __restrict__ Gpb, float* __restrict__ invn) {
  __shared__ float red[2];
  int row = blockIdx.x, t = threadIdx.x;
  const float4* src = (const float4*)(G + (size_t)perm[row] * DIM);
  float4 v = src[t];
  ushort4 b;
  b.x = f2bf(v.x); b.y = f2bf(v.y); b.z = f2bf(v.z); b.w = f2bf(v.w);
  *(ushort4*)(Gpb + (size_t)row * DIM + t * 4) = b;
  float ss = v.x * v.x + v.y * v.y + v.z * v.z + v.w * v.w;
  ss = waveReduce(ss);
  if ((t & 63) == 0) red[t >> 6] = ss;
  __syncthreads();
  if (t == 0) invn[row] = 1.f / fmaxf(sqrtf(red[0] + red[1]), 1e-12f);
}

__global__ void k_tobf16(const float4* __restrict__ src, ushort4* __restrict__ dst, int n4) {
  int i = blockIdx.x * blockDim.x + threadIdx.x;
  if (i < n4) {
    float4 v = src[i];
    ushort4 o;
    o.x = f2bf(v.x); o.y = f2bf(v.y); o.z = f2bf(v.z); o.w = f2bf(v.w);
    dst[i] = o;
  }
}

// per-class cosine-sim: 32x32 tiles (fp32 exact, same k-accumulation order)
__global__ __launch_bounds__(256) void k_sim(const float* __restrict__ G, const int* __restrict__ perm,
                                             const float* __restrict__ invn,
                                             const int* __restrict__ cnt, const int* __restrict__ off,
                                             float* __restrict__ sim) {
  int c = blockIdx.y;
  int n = min(cnt[c], CAP);
  int ti = blockIdx.x >> 2, tj = blockIdx.x & 3;
  if (ti * 32 >= n || tj * 32 >= n) return;
  int base = off[c];
  __shared__ float As[16][36];
  __shared__ float Bs[16][36];
  const int tx = threadIdx.x & 15, ty = threadIdx.x >> 4;
  const int lr = threadIdx.x >> 3, lq = threadIdx.x & 7;   // 32 rows x 8 k-pairs (float2)
  float acc[2][2] = {};
  int ra = ti * 32 + lr, rb = tj * 32 + lr;
  bool oka = ra < n, okb = rb < n;
  size_t ga = (size_t)perm[base + (oka ? ra : 0)] * DIM;
  size_t gb = (size_t)perm[base + (okb ? rb : 0)] * DIM;
  float sa = oka ? invn[base + ra] : 0.f;
  float sb = okb ? invn[base + rb] : 0.f;
  for (int k0 = 0; k0 < DIM; k0 += 16) {
    float2 va = *(const float2*)(G + ga + k0 + lq * 2);
    float2 vb = *(const float2*)(G + gb + k0 + lq * 2);
    __syncthreads();
    As[lq * 2 + 0][lr] = va.x * sa; As[lq * 2 + 1][lr] = va.y * sa;
    Bs[lq * 2 + 0][lr] = vb.x * sb; Bs[lq * 2 + 1][lr] = vb.y * sb;
    __syncthreads();
#pragma unroll
    for (int kk = 0; kk < 16; ++kk) {
      float2 a2 = *(const float2*)&As[kk][ty * 2];
      float2 b2 = *(const float2*)&Bs[kk][tx * 2];
      acc[0][0] += a2.x * b2.x; acc[0][1] += a2.x * b2.y;
      acc[1][0] += a2.y * b2.x; acc[1][1] += a2.y * b2.y;
    }
  }
#pragma unroll
  for (int i = 0; i < 2; ++i) {
    int gi = ti * 32 + ty * 2 + i;
    if (gi >= n) continue;
#pragma unroll
    for (int j = 0; j < 2; ++j) {
      int gj = tj * 32 + tx * 2 + j;
      if (gj >= n) continue;
      float v = acc[i][j];
      v = fminf(fmaxf(v, -1.0f + 1e-8f), 1.0f - 1e-8f);
      sim[((size_t)c * CAP + gi) * CAP + gj] = v;
    }
  }
}

// top-8 per row within class
__global__ __launch_bounds__(64) void k_topk(const float* __restrict__ sim, const int* __restrict__ cnt,
                                             const int* __restrict__ off, const int* __restrict__ clsp,
                                             int* __restrict__ t8) {
  int pr = blockIdx.x * 64 + threadIdx.x;
  if (pr >= NROWS) return;
  int c = clsp[pr];
  int n = min(cnt[c], CAP);
  int loc = pr - off[c];
  const float* row = sim + ((size_t)c * CAP + loc) * CAP;
  float bv[8]; int bi[8];
#pragma unroll
  for (int q = 0; q < 8; ++q) { bv[q] = -3e38f; bi[q] = -1; }
  for (int j = 0; j < n; ++j) {
    if (j == loc) continue;
    float v = row[j];
    if (v > bv[7]) {
      bv[7] = v; bi[7] = j;
#pragma unroll
      for (int q = 7; q > 0; --q) {
        if (bv[q] > bv[q - 1]) {
          float tv = bv[q]; bv[q] = bv[q - 1]; bv[q - 1] = tv;
          int tq = bi[q]; bi[q] = bi[q - 1]; bi[q - 1] = tq;
        }
      }
    }
  }
#pragma unroll
  for (int q = 0; q < 8; ++q) t8[pr * 8 + q] = bi[q];
}

// ---- build S pass 1: masked weights + row degree -> dinv (32 rows x 8 lanes per block) ----
__global__ __launch_bounds__(256) void k_buildS1(const float* __restrict__ sim, const int* __restrict__ cnt,
                                                 const int* __restrict__ off, const int* __restrict__ t8,
                                                 float alpha, float* __restrict__ S, float* __restrict__ dinv) {
  int c = blockIdx.x;
  int n = min(cnt[c], CAP);
  int i0 = blockIdx.y * 32;
  if (i0 >= n) return;
  int base = off[c];
  __shared__ int sh8[CAP * 8];
  for (int i = threadIdx.x; i < n * 8; i += 256) sh8[i] = t8[base * 8 + i];
  __syncthreads();
  int r = threadIdx.x >> 3;   // 0..31
  int lj = threadIdx.x & 7;
  int i = i0 + r;
  float d = 0.f;
  if (i < n) {
    int my8[8];
#pragma unroll
    for (int q = 0; q < 8; ++q) my8[q] = sh8[i * 8 + q];
    const float* srow = sim + ((size_t)c * CAP + i) * CAP;
    float* wrow = S + ((size_t)c * CAP + i) * CAP;
    for (int j = lj; j < n; j += 8) {
      float w;
      if (j == i) w = 1e-6f;
      else {
        bool m = false;
#pragma unroll
        for (int q = 0; q < 8; ++q) m = m || (my8[q] == j) || (sh8[j * 8 + q] == i);
        w = m ? alpha * fmaxf(srow[j], 0.f) : 0.f;
      }
      wrow[j] = w;
      d += w;
    }
  }
  // 8-lane group sum (groups are within a wave)
  d += __shfl_xor(d, 1);
  d += __shfl_xor(d, 2);
  d += __shfl_xor(d, 4);
  if (lj == 0 && i < n) dinv[c * CAP + i] = 1.f / sqrtf(fmaxf(d, 1e-8f));
}

// ---- build S pass 2: S[i][j] *= dinv_i * dinv_j (coalesced) ----
__global__ __launch_bounds__(256) void k_buildS2(float* __restrict__ S, const float* __restrict__ dinv,
                                                 const int* __restrict__ cnt) {
  int c = blockIdx.x;
  int n = min(cnt[c], CAP);
  int i0 = blockIdx.y * 32;
  if (i0 >= n) return;
  __shared__ float sd[CAP];
  for (int k = threadIdx.x; k < n; k += 256) sd[k] = dinv[c * CAP + k];
  __syncthreads();
  for (int p = threadIdx.x; p < 32 * CAP; p += 256) {
    int r = p >> 7, j = p & (CAP - 1);
    int i = i0 + r;
    if (i < n && j < n)
      S[((size_t)c * CAP + i) * CAP + j] *= sd[i] * sd[j];
  }
}

// ------------- bf16 MFMA GEMM: C[4096 x N] = A[4096 x 512] @ B[N x 512]^T -------------
// 128x64 tile, 256 threads (4 waves, each 32 rows x 64 cols)
__global__ __launch_bounds__(256) void k_gemm_bf16(const short* __restrict__ A, const short* __restrict__ B,
                                                   float* __restrict__ C, int N) {
  __shared__ short As[128][40];
  __shared__ short Bs[64][40];
  const int row0 = blockIdx.x * 128, col0 = blockIdx.y * 64;
  const int t = threadIdx.x;
  const int lane = t & 63, wv = t >> 6;
  const int fr = lane & 15, kg = lane >> 4;
  const int sra = t >> 1, ska = (t & 1) * 16;
  const int srb = t >> 2, skb = (t & 3) * 8;
  const short* pa = A + (size_t)(row0 + sra) * DIM + ska;
  const short* pb = B + (size_t)(col0 + srb) * DIM + skb;
  f32x4 acc[2][4] = {};
  for (int kt = 0; kt < DIM; kt += 32) {
    short8v a0 = *(const short8v*)(pa + kt);
    short8v a1 = *(const short8v*)(pa + kt + 8);
    short8v b0 = *(const short8v*)(pb + kt);
    __syncthreads();
    *(short8v*)&As[sra][ska] = a0;
    *(short8v*)&As[sra][ska + 8] = a1;
    *(short8v*)&Bs[srb][skb] = b0;
    __syncthreads();
    short8v af[2], bf[4];
#pragma unroll
    for (int i = 0; i < 2; ++i) af[i] = *(const short8v*)&As[wv * 32 + i * 16 + fr][kg * 8];
#pragma unroll
    for (int j = 0; j < 4; ++j) bf[j] = *(const short8v*)&Bs[j * 16 + fr][kg * 8];
#pragma unroll
    for (int i = 0; i < 2; ++i)
#pragma unroll
      for (int j = 0; j < 4; ++j)
        acc[i][j] = __builtin_amdgcn_mfma_f32_16x16x32_bf16(af[i], bf[j], acc[i][j], 0, 0, 0);
  }
#pragma unroll
  for (int i = 0; i < 2; ++i) {
    int r0 = row0 + wv * 32 + i * 16 + kg * 4;
#pragma unroll
    for (int j = 0; j < 4; ++j) {
      int cc = col0 + j * 16 + fr;
#pragma unroll
      for (int r = 0; r < 4; ++r)
        C[(size_t)(r0 + r) * N + cc] = acc[i][j][r];
    }
  }
}

// Y[base+i][:] = sum_j S[c][i][j] * X[base+j][:] (+ optional residual) — 32 rows x 64 cols per block
__global__ __launch_bounds__(256) void k_spmm2(const float* __restrict__ S, const float* __restrict__ X,
                                               const float* __restrict__ Gfeat, const int* __restrict__ perm,
                                               float* __restrict__ Y, unsigned short* __restrict__ Yb,
                                               const int* __restrict__ cnt, const int* __restrict__ off) {
  int c = blockIdx.x;
  int n = min(cnt[c], CAP);
  int i0 = blockIdx.z * 32;
  if (i0 >= n) return;
  int base = off[c];
  int col = blockIdx.y * 64 + (threadIdx.x & 63);
  int ty = threadIdx.x >> 6;  // 4 groups x 8 rows
  __shared__ float sS[32][CAP];
  for (int idx = threadIdx.x; idx < 32 * n; idx += 256) {
    int r = idx / n, j = idx - r * n;
    sS[r][j] = (i0 + r < n) ? S[((size_t)c * CAP + i0 + r) * CAP + j] : 0.f;
  }
  __syncthreads();
  float acc[8] = {0, 0, 0, 0, 0, 0, 0, 0};
  for (int j = 0; j < n; ++j) {
    float x = X[(size_t)(base + j) * DIM + col];
#pragma unroll
    for (int ii = 0; ii < 8; ++ii) acc[ii] += sS[ty * 8 + ii][j] * x;
  }
#pragma unroll
  for (int ii = 0; ii < 8; ++ii) {
    int r = i0 + ty * 8 + ii;
    if (r < n) {
      size_t o = (size_t)(base + r) * DIM + col;
      float v = acc[ii];
      if (Gfeat) v += Gfeat[(size_t)perm[base + r] * DIM + col];
      if (Yb) Yb[o] = f2bf(v);
      else Y[o] = v;
    }
  }
}

// column partial sums / sumsq (32 rows per block, no atomics)
__global__ __launch_bounds__(256) void k_colstats(const float* __restrict__ X, float* __restrict__ part) {
  int rb = blockIdx.x, t = threadIdx.x;
#pragma unroll
  for (int cp = 0; cp < 2; ++cp) {
    int col = cp * 256 + t;
    float s = 0.f, s2 = 0.f;
    for (int r = 0; r < 32; ++r) {
      float v = X[(size_t)(rb * 32 + r) * DIM + col];
      s += v; s2 += v * v;
    }
    part[rb * 1024 + col] = s;
    part[rb * 1024 + 512 + col] = s2;
  }
}

__global__ __launch_bounds__(64) void k_bnfin(const float* __restrict__ part, const float* __restrict__ gamma,
                                              const float* __restrict__ beta, float* __restrict__ sc) {
  int k = blockIdx.x * 64 + threadIdx.x;
  float s = 0.f, s2 = 0.f;
  for (int b = 0; b < NROWS / 32; ++b) {
    s += part[b * 1024 + k];
    s2 += part[b * 1024 + 512 + k];
  }
  float m = s * (1.f / NROWS);
  float var = s2 * (1.f / NROWS) - m * m;
  float sg = gamma[k] / sqrtf(var + 1e-5f);
  sc[k] = sg;
  sc[DIM + k] = beta[k] - m * sg;
}

// BN+ReLU, writes bf16
__global__ __launch_bounds__(256) void k_bnrelu(const float4* __restrict__ X, const float* __restrict__ sc,
                                                ushort4* __restrict__ Yb) {
  int i = blockIdx.x * blockDim.x + threadIdx.x;
  int cb = (i * 4) & (DIM - 1);
  float4 v = X[i];
  ushort4 o;
  o.x = f2bf(fmaxf(v.x * sc[cb + 0] + sc[DIM + cb + 0], 0.f));
  o.y = f2bf(fmaxf(v.y * sc[cb + 1] + sc[DIM + cb + 1], 0.f));
  o.z = f2bf(fmaxf(v.z * sc[cb + 2] + sc[DIM + cb + 2], 0.f));
  o.w = f2bf(fmaxf(v.w * sc[cb + 3] + sc[DIM + cb + 3], 0.f));
  Yb[i] = o;
}

__global__ __launch_bounds__(192) void k_rownormP(float* __restrict__ P) {
  __shared__ float red[3];
  __shared__ float s_inv;
  int row = blockIdx.x, t = threadIdx.x;
  float4* p = (float4*)(P + (size_t)row * PD);
  float4 v = p[t];
  float ss = v.x * v.x + v.y * v.y + v.z * v.z + v.w * v.w;
  ss = waveReduce(ss);
  if ((t & 63) == 0) red[t >> 6] = ss;
  __syncthreads();
  if (t == 0) s_inv = 1.f / fmaxf(sqrtf(red[0] + red[1] + red[2]), 1e-12f);
  __syncthreads();
  float inv = s_inv;
  v.x *= inv; v.y *= inv; v.z *= inv; v.w *= inv;
  p[t] = v;
}

__global__ __launch_bounds__(256) void k_lossdiff(const float* __restrict__ A, const float* __restrict__ B,
                                                  int n, float coef, float* __restrict__ acc) {
  float s = 0.f;
  for (int i = blockIdx.x * blockDim.x + threadIdx.x; i < n; i += gridDim.x * blockDim.x) {
    float d = A[i] - B[i];
    s += d * d;
  }
  s = blockReduce(s);
  if (threadIdx.x == 0) atomicAdd(acc, s * coef);
}

__global__ __launch_bounds__(256) void k_lossS(const float* __restrict__ Sa, const float* __restrict__ Sb,
                                               const int* __restrict__ cnt, float target, float coef,
                                               float* __restrict__ acc) {
  int c = blockIdx.x;
  int n = min(cnt[c], CAP);
  float s = 0.f;
  for (int p = threadIdx.x; p < n * n; p += 256) {
    int i = p / n, j = p % n;
    size_t o = ((size_t)c * CAP + i) * CAP + j;
    float d = Sb ? (Sa[o] - Sb[o]) : (Sa[o] - target);
    s += d * d;
  }
  s = blockReduce(s);
  if (threadIdx.x == 0) atomicAdd(acc, s * coef);
}

__global__ void k_final(const float* __restrict__ acc, float* __restrict__ out) {
  if (threadIdx.x == 0) out[0] = acc[0];
}

// ---------------- host ----------------
extern "C" void kernel_launch(void* const* d_in, const int* in_sizes, int n_in,
                              void* d_out, int out_size, void* d_ws, size_t ws_size,
                              hipStream_t stream) {
  const float* feats = (const float*)d_in[0];
  const int* labels = (const int*)d_in[1];
  const float* fc1 = (const float*)d_in[2];
  const float* fc2 = (const float*)d_in[3];
  const float* gamma = (const float*)d_in[4];
  const float* beta = (const float*)d_in[5];
  const float* proj = (const float*)d_in[6];
  float* out = (float*)d_out;

  char* w = (char*)d_ws;
  auto alloc = [&](size_t bytes) { char* p = w; w += (bytes + 255) & ~(size_t)255; return p; };
  float* bufA = (float*)alloc((size_t)NROWS * DIM * 4);
  float* bufB = (float*)alloc((size_t)NROWS * DIM * 4);
  unsigned short* Gpb = (unsigned short*)alloc((size_t)NROWS * DIM * 2);
  unsigned short* actb = (unsigned short*)alloc((size_t)NROWS * DIM * 2);
  unsigned short* W1b = (unsigned short*)alloc((size_t)3 * DIM * DIM * 2);
  unsigned short* W2b = (unsigned short*)alloc((size_t)3 * DIM * DIM * 2);
  unsigned short* Pjb = (unsigned short*)alloc((size_t)PD * DIM * 2);
  float* sim  = (float*)alloc((size_t)NCLS * CAP * CAP * 4);
  float* S0   = (float*)alloc((size_t)NCLS * CAP * CAP * 4);
  float* S1   = (float*)alloc((size_t)NCLS * CAP * CAP * 4);
  float* PA   = (float*)alloc((size_t)NROWS * PD * 4);
  float* PB   = (float*)alloc((size_t)NROWS * PD * 4);
  float* invn = (float*)alloc(NROWS * 4);
  float* dinv = (float*)alloc(NCLS * CAP * 4);
  float* part = (float*)alloc((size_t)(NROWS / 32) * 1024 * 4);
  float* bnsc = (float*)alloc(2 * DIM * 4);
  float* acc  = (float*)alloc(256);
  int* cnt  = (int*)alloc(NCLS * 4);
  int* offc = (int*)alloc((NCLS + 1) * 4);
  int* perm = (int*)alloc(NROWS * 4);
  int* clsp = (int*)alloc(NROWS * 4);
  int* t8   = (int*)alloc(NROWS * 8 * 4);
  int* chunkCnt  = (int*)alloc(16 * NCLS * 4);
  int* chunkBase = (int*)alloc(16 * NCLS * 4);

  const float LAM_K = 64.f, LAM_Z = 16.f, SIGMA = 0.99f;
  const float cK = LAM_K / ((float)NROWS * (float)NROWS);
  const float cZ = LAM_Z / ((float)NROWS * (float)PD);
  const float cI = 1.f / ((float)NROWS * (float)NROWS);

  hipLaunchKernelGGL(k_zerof, dim3(1), dim3(64), 0, stream, acc, 4);
  hipLaunchKernelGGL(k_hist, dim3(16), dim3(256), 0, stream, labels, chunkCnt);
  hipLaunchKernelGGL(k_scan, dim3(1), dim3(64), 0, stream, chunkCnt, cnt, offc, chunkBase);
  hipLaunchKernelGGL(k_scatter, dim3(16), dim3(256), 0, stream, labels, chunkBase, perm, clsp);
  // all weights -> bf16 once
  hipLaunchKernelGGL(k_tobf16, dim3((3 * DIM * DIM / 4 + 255) / 256), dim3(256), 0, stream,
                     (const float4*)fc1, (ushort4*)W1b, 3 * DIM * DIM / 4);
  hipLaunchKernelGGL(k_tobf16, dim3((3 * DIM * DIM / 4 + 255) / 256), dim3(256), 0, stream,
                     (const float4*)fc2, (ushort4*)W2b, 3 * DIM * DIM / 4);
  hipLaunchKernelGGL(k_tobf16, dim3((PD * DIM / 4 + 255) / 256), dim3(256), 0, stream,
                     (const float4*)proj, (ushort4*)Pjb, PD * DIM / 4);

  float* Sbuf[2] = {S0, S1};
  float* Pbuf[2] = {PA, PB};

  for (int l = 0; l < 3; ++l) {
    const float* G = feats + (size_t)l * NROWS * DIM;
    float alpha = 1.0f + 0.1f * l;
    float* Scur = Sbuf[l & 1];
    float* Sprev = Sbuf[(l & 1) ^ 1];
    float* Pcur = Pbuf[l & 1];
    float* Pprev = Pbuf[(l & 1) ^ 1];

    hipLaunchKernelGGL(k_prep, dim3(NROWS), dim3(128), 0, stream, G, perm, Gpb, invn);
    hipLaunchKernelGGL(k_sim, dim3(16, NCLS), dim3(256), 0, stream, G, perm, invn, cnt, offc, sim);
    hipLaunchKernelGGL(k_topk, dim3(NROWS / 64), dim3(64), 0, stream, sim, cnt, offc, clsp, t8);
    hipLaunchKernelGGL(k_buildS1, dim3(NCLS, CAP / 32), dim3(256), 0, stream, sim, cnt, offc, t8, alpha, Scur, dinv);
    hipLaunchKernelGGL(k_buildS2, dim3(NCLS, CAP / 32), dim3(256), 0, stream, Scur, dinv, cnt);

    // T1 = Gp @ w1^T  (bf16 MFMA)
    hipLaunchKernelGGL(k_gemm_bf16, dim3(NROWS / 128, DIM / 64), dim3(256), 0, stream,
                       (const short*)Gpb, (const short*)(W1b + (size_t)l * DIM * DIM), bufA, DIM);
    // T2 = S @ T1 (fp32)
    hipLaunchKernelGGL(k_spmm2, dim3(NCLS, DIM / 64, CAP / 32), dim3(256), 0, stream, Scur, bufA,
                       (const float*)nullptr, (const int*)nullptr, bufB, (unsigned short*)nullptr, cnt, offc);
    // BN stats + relu -> bf16 T3
    hipLaunchKernelGGL(k_colstats, dim3(NROWS / 32), dim3(256), 0, stream, bufB, part);
    hipLaunchKernelGGL(k_bnfin, dim3(DIM / 64), dim3(64), 0, stream, part, gamma + (size_t)l * DIM, beta + (size_t)l * DIM, bnsc);
    hipLaunchKernelGGL(k_bnrelu, dim3(NROWS * DIM / 4 / 256), dim3(256), 0, stream,
                       (const float4*)bufB, bnsc, (ushort4*)actb);
    // T4 = T3 @ w2^T -> bufB
    hipLaunchKernelGGL(k_gemm_bf16, dim3(NROWS / 128, DIM / 64), dim3(256), 0, stream,
                       (const short*)actb, (const short*)(W2b + (size_t)l * DIM * DIM), bufB, DIM);
    // Z = S @ T4 + G (residual via perm) -> bf16 Zb (actb)
    hipLaunchKernelGGL(k_spmm2, dim3(NCLS, DIM / 64, CAP / 32), dim3(256), 0, stream, Scur, bufB,
                       G, perm, (float*)nullptr, actb, cnt, offc);
    // P = l2norm(Z @ proj^T)
    hipLaunchKernelGGL(k_gemm_bf16, dim3(NROWS / 128, PD / 64), dim3(256), 0, stream,
                       (const short*)actb, (const short*)Pjb, Pcur, PD);
    hipLaunchKernelGGL(k_rownormP, dim3(NROWS), dim3(192), 0, stream, Pcur);

    if (l >= 1) {
      hipLaunchKernelGGL(k_lossS, dim3(NCLS), dim3(256), 0, stream, Sprev, Scur, cnt, 0.f, cK, acc);
      hipLaunchKernelGGL(k_lossdiff, dim3(1024), dim3(256), 0, stream, Pprev, Pcur, NROWS * PD, cZ, acc);
    }
    if (l == 2) {
      hipLaunchKernelGGL(k_lossS, dim3(NCLS), dim3(256), 0, stream, Scur, (const float*)nullptr, cnt, SIGMA, cI, acc);
    }
  }
  hipLaunchKernelGGL(k_final, dim3(1), dim3(64), 0, stream, acc, out);
}

// Round 5
// 536.351 us; speedup vs baseline: 2.9188x; 1.1735x over previous
//
#include <hip/hip_runtime.h>
#include <math.h>

#define NROWS 4096
#define DIM   512
#define NCLS  64
#define CAP   128
#define PD    768

typedef __attribute__((ext_vector_type(8))) short short8v;
typedef __attribute__((ext_vector_type(4))) float f32x4;

__device__ __forceinline__ unsigned short f2bf(float f) {
  unsigned u = __float_as_uint(f);
  unsigned r = (u + 0x7FFF + ((u >> 16) & 1)) >> 16;
  return (unsigned short)r;
}

// ---------------- reduction helpers ----------------
__device__ __forceinline__ float waveReduce(float v) {
#pragma unroll
  for (int o = 32; o > 0; o >>= 1) v += __shfl_down(v, o);
  return v;
}

__device__ __forceinline__ float blockReduce(float v) {
  __shared__ float sh[4];
  int lane = threadIdx.x & 63, wv = threadIdx.x >> 6;
  v = waveReduce(v);
  if (lane == 0) sh[wv] = v;
  __syncthreads();
  float t = 0.f;
  if (threadIdx.x == 0) {
    int nw = (blockDim.x + 63) >> 6;
    for (int i = 0; i < nw; ++i) t += sh[i];
  }
  return t;
}

// ---------------- misc ----------------
__global__ void k_zerof(float* p, int n) {
  for (int i = blockIdx.x * blockDim.x + threadIdx.x; i < n; i += gridDim.x * blockDim.x) p[i] = 0.f;
}

// ---------------- parallel stable bucketing ----------------
__global__ __launch_bounds__(256) void k_hist(const int* __restrict__ labels, int* __restrict__ chunkCnt) {
  __shared__ int h[NCLS];
  int t = threadIdx.x;
  if (t < NCLS) h[t] = 0;
  __syncthreads();
  atomicAdd(&h[labels[blockIdx.x * 256 + t]], 1);
  __syncthreads();
  if (t < NCLS) chunkCnt[blockIdx.x * NCLS + t] = h[t];
}

__global__ void k_scan(const int* __restrict__ chunkCnt, int* __restrict__ cnt,
                       int* __restrict__ off, int* __restrict__ chunkBase) {
  __shared__ int sc[NCLS];
  int c = threadIdx.x;  // 64 threads
  int tot = 0;
  for (int b = 0; b < 16; ++b) tot += chunkCnt[b * NCLS + c];
  cnt[c] = tot;
  sc[c] = tot;
  __syncthreads();
  if (c == 0) {
    int s = 0;
    for (int i = 0; i < NCLS; ++i) { int tv = sc[i]; sc[i] = s; s += tv; }
  }
  __syncthreads();
  int run = sc[c];
  off[c] = run;
  for (int b = 0; b < 16; ++b) { chunkBase[b * NCLS + c] = run; run += chunkCnt[b * NCLS + c]; }
  if (c == 0) off[NCLS] = NROWS;
}

__global__ __launch_bounds__(256) void k_scatter(const int* __restrict__ labels, const int* __restrict__ chunkBase,
                                                 int* __restrict__ perm, int* __restrict__ clsp) {
  __shared__ int lab[256];
  int t = threadIdx.x;
  int r = blockIdx.x * 256 + t;
  int c = labels[r];
  lab[t] = c;
  __syncthreads();
  int rank = 0;
  for (int j = 0; j < t; ++j) rank += (lab[j] == c);
  int pos = chunkBase[blockIdx.x * NCLS + c] + rank;
  perm[pos] = r;
  clsp[pos] = c;
}

// gathered bf16 copy + row inverse norms (fp32)
__global__ __launch_bounds__(128) void k_prep(const float* __restrict__ G, const int* __restrict__ perm,
                                              unsigned short* __restrict__ Gpb, float* __restrict__ invn) {
  __shared__ float red[2];
  int row = blockIdx.x, t = threadIdx.x;
  const float4* src = (const float4*)(G + (size_t)perm[row] * DIM);
  float4 v = src[t];
  ushort4 b;
  b.x = f2bf(v.x); b.y = f2bf(v.y); b.z = f2bf(v.z); b.w = f2bf(v.w);
  *(ushort4*)(Gpb + (size_t)row * DIM + t * 4) = b;
  float ss = v.x * v.x + v.y * v.y + v.z * v.z + v.w * v.w;
  ss = waveReduce(ss);
  if ((t & 63) == 0) red[t >> 6] = ss;
  __syncthreads();
  if (t == 0) invn[row] = 1.f / fmaxf(sqrtf(red[0] + red[1]), 1e-12f);
}

__global__ void k_tobf16(const float4* __restrict__ src, ushort4* __restrict__ dst, int n4) {
  int i = blockIdx.x * blockDim.x + threadIdx.x;
  if (i < n4) {
    float4 v = src[i];
    ushort4 o;
    o.x = f2bf(v.x); o.y = f2bf(v.y); o.z = f2bf(v.z); o.w = f2bf(v.w);
    dst[i] = o;
  }
}

// per-class cosine-sim via bf16 MFMA: 32x32 tile per block, 4 waves = 4 quadrants.
// sim_ij = clip(invn_i * invn_j * <Gb_i, Gb_j>)
__global__ __launch_bounds__(256) void k_sim(const unsigned short* __restrict__ Gpb,
                                             const float* __restrict__ invn,
                                             const int* __restrict__ cnt, const int* __restrict__ off,
                                             float* __restrict__ sim) {
  int c = blockIdx.y;
  int n = min(cnt[c], CAP);
  int ti = blockIdx.x >> 2, tj = blockIdx.x & 3;
  if (ti * 32 >= n || tj * 32 >= n) return;
  int base = off[c];
  __shared__ short As[32][40];
  __shared__ short Bs[32][40];
  const int t = threadIdx.x;
  const int lane = t & 63, wv = t >> 6;
  const int qi = wv >> 1, qj = wv & 1;
  const int fr = lane & 15, kg = lane >> 4;
  // staging: threads 0-127 stage A (32 rows x 32 k), threads 128-255 stage B; 16B per thread
  const int half = t >> 7, tt = t & 127;
  const int srow = tt >> 2, scol = (tt & 3) * 8;
  int gr = (half ? tj : ti) * 32 + srow;
  const unsigned short* ps = Gpb + (size_t)(base + min(gr, n - 1)) * DIM + scol;
  short* dst = half ? &Bs[srow][scol] : &As[srow][scol];
  f32x4 acc = {};
  for (int k0 = 0; k0 < DIM; k0 += 32) {
    short8v v = *(const short8v*)(ps + k0);
    __syncthreads();
    *(short8v*)dst = v;
    __syncthreads();
    short8v af = *(const short8v*)&As[qi * 16 + fr][kg * 8];
    short8v bf = *(const short8v*)&Bs[qj * 16 + fr][kg * 8];
    acc = __builtin_amdgcn_mfma_f32_16x16x32_bf16(af, bf, acc, 0, 0, 0);
  }
  int gj = tj * 32 + qj * 16 + fr;
  int r0 = ti * 32 + qi * 16 + kg * 4;
  if (gj < n) {
    float sj = invn[base + gj];
#pragma unroll
    for (int r = 0; r < 4; ++r) {
      int gi = r0 + r;
      if (gi < n) {
        float v = acc[r] * invn[base + gi] * sj;
        v = fminf(fmaxf(v, -1.0f + 1e-8f), 1.0f - 1e-8f);
        sim[((size_t)c * CAP + gi) * CAP + gj] = v;
      }
    }
  }
}

// top-8 per row within class
__global__ __launch_bounds__(64) void k_topk(const float* __restrict__ sim, const int* __restrict__ cnt,
                                             const int* __restrict__ off, const int* __restrict__ clsp,
                                             int* __restrict__ t8) {
  int pr = blockIdx.x * 64 + threadIdx.x;
  if (pr >= NROWS) return;
  int c = clsp[pr];
  int n = min(cnt[c], CAP);
  int loc = pr - off[c];
  const float* row = sim + ((size_t)c * CAP + loc) * CAP;
  float bv[8]; int bi[8];
#pragma unroll
  for (int q = 0; q < 8; ++q) { bv[q] = -3e38f; bi[q] = -1; }
  for (int j = 0; j < n; ++j) {
    if (j == loc) continue;
    float v = row[j];
    if (v > bv[7]) {
      bv[7] = v; bi[7] = j;
#pragma unroll
      for (int q = 7; q > 0; --q) {
        if (bv[q] > bv[q - 1]) {
          float tv = bv[q]; bv[q] = bv[q - 1]; bv[q - 1] = tv;
          int tq = bi[q]; bi[q] = bi[q - 1]; bi[q - 1] = tq;
        }
      }
    }
  }
#pragma unroll
  for (int q = 0; q < 8; ++q) t8[pr * 8 + q] = bi[q];
}

// ---- build S pass 1: masked weights + row degree -> dinv (32 rows x 8 lanes per block) ----
__global__ __launch_bounds__(256) void k_buildS1(const float* __restrict__ sim, const int* __restrict__ cnt,
                                                 const int* __restrict__ off, const int* __restrict__ t8,
                                                 float alpha, float* __restrict__ S, float* __restrict__ dinv) {
  int c = blockIdx.x;
  int n = min(cnt[c], CAP);
  int i0 = blockIdx.y * 32;
  if (i0 >= n) return;
  int base = off[c];
  __shared__ int sh8[CAP * 8];
  for (int i = threadIdx.x; i < n * 8; i += 256) sh8[i] = t8[base * 8 + i];
  __syncthreads();
  int r = threadIdx.x >> 3;   // 0..31
  int lj = threadIdx.x & 7;
  int i = i0 + r;
  float d = 0.f;
  if (i < n) {
    int my8[8];
#pragma unroll
    for (int q = 0; q < 8; ++q) my8[q] = sh8[i * 8 + q];
    const float* srow = sim + ((size_t)c * CAP + i) * CAP;
    float* wrow = S + ((size_t)c * CAP + i) * CAP;
    for (int j = lj; j < n; j += 8) {
      float w;
      if (j == i) w = 1e-6f;
      else {
        bool m = false;
#pragma unroll
        for (int q = 0; q < 8; ++q) m = m || (my8[q] == j) || (sh8[j * 8 + q] == i);
        w = m ? alpha * fmaxf(srow[j], 0.f) : 0.f;
      }
      wrow[j] = w;
      d += w;
    }
  }
  // 8-lane group sum (groups are within a wave)
  d += __shfl_xor(d, 1);
  d += __shfl_xor(d, 2);
  d += __shfl_xor(d, 4);
  if (lj == 0 && i < n) dinv[c * CAP + i] = 1.f / sqrtf(fmaxf(d, 1e-8f));
}

// ---- build S pass 2: S[i][j] *= dinv_i * dinv_j (coalesced) ----
__global__ __launch_bounds__(256) void k_buildS2(float* __restrict__ S, const float* __restrict__ dinv,
                                                 const int* __restrict__ cnt) {
  int c = blockIdx.x;
  int n = min(cnt[c], CAP);
  int i0 = blockIdx.y * 32;
  if (i0 >= n) return;
  __shared__ float sd[CAP];
  for (int k = threadIdx.x; k < n; k += 256) sd[k] = dinv[c * CAP + k];
  __syncthreads();
  for (int p = threadIdx.x; p < 32 * CAP; p += 256) {
    int r = p >> 7, j = p & (CAP - 1);
    int i = i0 + r;
    if (i < n && j < n)
      S[((size_t)c * CAP + i) * CAP + j] *= sd[i] * sd[j];
  }
}

// ------------- bf16 MFMA GEMM: C[4096 x N] = A[4096 x 512] @ B[N x 512]^T -------------
// 128x64 tile, 256 threads (4 waves, each 32 rows x 64 cols)
__global__ __launch_bounds__(256) void k_gemm_bf16(const short* __restrict__ A, const short* __restrict__ B,
                                                   float* __restrict__ C, int N) {
  __shared__ short As[128][40];
  __shared__ short Bs[64][40];
  const int row0 = blockIdx.x * 128, col0 = blockIdx.y * 64;
  const int t = threadIdx.x;
  const int lane = t & 63, wv = t >> 6;
  const int fr = lane & 15, kg = lane >> 4;
  const int sra = t >> 1, ska = (t & 1) * 16;
  const int srb = t >> 2, skb = (t & 3) * 8;
  const short* pa = A + (size_t)(row0 + sra) * DIM + ska;
  const short* pb = B + (size_t)(col0 + srb) * DIM + skb;
  f32x4 acc[2][4] = {};
  for (int kt = 0; kt < DIM; kt += 32) {
    short8v a0 = *(const short8v*)(pa + kt);
    short8v a1 = *(const short8v*)(pa + kt + 8);
    short8v b0 = *(const short8v*)(pb + kt);
    __syncthreads();
    *(short8v*)&As[sra][ska] = a0;
    *(short8v*)&As[sra][ska + 8] = a1;
    *(short8v*)&Bs[srb][skb] = b0;
    __syncthreads();
    short8v af[2], bf[4];
#pragma unroll
    for (int i = 0; i < 2; ++i) af[i] = *(const short8v*)&As[wv * 32 + i * 16 + fr][kg * 8];
#pragma unroll
    for (int j = 0; j < 4; ++j) bf[j] = *(const short8v*)&Bs[j * 16 + fr][kg * 8];
#pragma unroll
    for (int i = 0; i < 2; ++i)
#pragma unroll
      for (int j = 0; j < 4; ++j)
        acc[i][j] = __builtin_amdgcn_mfma_f32_16x16x32_bf16(af[i], bf[j], acc[i][j], 0, 0, 0);
  }
#pragma unroll
  for (int i = 0; i < 2; ++i) {
    int r0 = row0 + wv * 32 + i * 16 + kg * 4;
#pragma unroll
    for (int j = 0; j < 4; ++j) {
      int cc = col0 + j * 16 + fr;
#pragma unroll
      for (int r = 0; r < 4; ++r)
        C[(size_t)(r0 + r) * N + cc] = acc[i][j][r];
    }
  }
}

// Y[base+i][:] = sum_j S[c][i][j] * X[base+j][:] (+ optional residual) — 32 rows x 64 cols per block
__global__ __launch_bounds__(256) void k_spmm2(const float* __restrict__ S, const float* __restrict__ X,
                                               const float* __restrict__ Gfeat, const int* __restrict__ perm,
                                               float* __restrict__ Y, unsigned short* __restrict__ Yb,
                                               const int* __restrict__ cnt, const int* __restrict__ off) {
  int c = blockIdx.x;
  int n = min(cnt[c], CAP);
  int i0 = blockIdx.z * 32;
  if (i0 >= n) return;
  int base = off[c];
  int col = blockIdx.y * 64 + (threadIdx.x & 63);
  int ty = threadIdx.x >> 6;  // 4 groups x 8 rows
  __shared__ float sS[32][CAP];
  for (int idx = threadIdx.x; idx < 32 * n; idx += 256) {
    int r = idx / n, j = idx - r * n;
    sS[r][j] = (i0 + r < n) ? S[((size_t)c * CAP + i0 + r) * CAP + j] : 0.f;
  }
  __syncthreads();
  float acc[8] = {0, 0, 0, 0, 0, 0, 0, 0};
  for (int j = 0; j < n; ++j) {
    float x = X[(size_t)(base + j) * DIM + col];
#pragma unroll
    for (int ii = 0; ii < 8; ++ii) acc[ii] += sS[ty * 8 + ii][j] * x;
  }
#pragma unroll
  for (int ii = 0; ii < 8; ++ii) {
    int r = i0 + ty * 8 + ii;
    if (r < n) {
      size_t o = (size_t)(base + r) * DIM + col;
      float v = acc[ii];
      if (Gfeat) v += Gfeat[(size_t)perm[base + r] * DIM + col];
      if (Yb) Yb[o] = f2bf(v);
      else Y[o] = v;
    }
  }
}

// column partial sums / sumsq (32 rows per block, no atomics)
__global__ __launch_bounds__(256) void k_colstats(const float* __restrict__ X, float* __restrict__ part) {
  int rb = blockIdx.x, t = threadIdx.x;
#pragma unroll
  for (int cp = 0; cp < 2; ++cp) {
    int col = cp * 256 + t;
    float s = 0.f, s2 = 0.f;
    for (int r = 0; r < 32; ++r) {
      float v = X[(size_t)(rb * 32 + r) * DIM + col];
      s += v; s2 += v * v;
    }
    part[rb * 1024 + col] = s;
    part[rb * 1024 + 512 + col] = s2;
  }
}

__global__ __launch_bounds__(64) void k_bnfin(const float* __restrict__ part, const float* __restrict__ gamma,
                                              const float* __restrict__ beta, float* __restrict__ sc) {
  int k = blockIdx.x * 64 + threadIdx.x;
  float s = 0.f, s2 = 0.f;
  for (int b = 0; b < NROWS / 32; ++b) {
    s += part[b * 1024 + k];
    s2 += part[b * 1024 + 512 + k];
  }
  float m = s * (1.f / NROWS);
  float var = s2 * (1.f / NROWS) - m * m;
  float sg = gamma[k] / sqrtf(var + 1e-5f);
  sc[k] = sg;
  sc[DIM + k] = beta[k] - m * sg;
}

// BN+ReLU, writes bf16
__global__ __launch_bounds__(256) void k_bnrelu(const float4* __restrict__ X, const float* __restrict__ sc,
                                                ushort4* __restrict__ Yb) {
  int i = blockIdx.x * blockDim.x + threadIdx.x;
  int cb = (i * 4) & (DIM - 1);
  float4 v = X[i];
  ushort4 o;
  o.x = f2bf(fmaxf(v.x * sc[cb + 0] + sc[DIM + cb + 0], 0.f));
  o.y = f2bf(fmaxf(v.y * sc[cb + 1] + sc[DIM + cb + 1], 0.f));
  o.z = f2bf(fmaxf(v.z * sc[cb + 2] + sc[DIM + cb + 2], 0.f));
  o.w = f2bf(fmaxf(v.w * sc[cb + 3] + sc[DIM + cb + 3], 0.f));
  Yb[i] = o;
}

__global__ __launch_bounds__(192) void k_rownormP(float* __restrict__ P) {
  __shared__ float red[3];
  __shared__ float s_inv;
  int row = blockIdx.x, t = threadIdx.x;
  float4* p = (float4*)(P + (size_t)row * PD);
  float4 v = p[t];
  float ss = v.x * v.x + v.y * v.y + v.z * v.z + v.w * v.w;
  ss = waveReduce(ss);
  if ((t & 63) == 0) red[t >> 6] = ss;
  __syncthreads();
  if (t == 0) s_inv = 1.f / fmaxf(sqrtf(red[0] + red[1] + red[2]), 1e-12f);
  __syncthreads();
  float inv = s_inv;
  v.x *= inv; v.y *= inv; v.z *= inv; v.w *= inv;
  p[t] = v;
}

__global__ __launch_bounds__(256) void k_lossdiff(const float* __restrict__ A, const float* __restrict__ B,
                                                  int n, float coef, float* __restrict__ acc) {
  float s = 0.f;
  for (int i = blockIdx.x * blockDim.x + threadIdx.x; i < n; i += gridDim.x * blockDim.x) {
    float d = A[i] - B[i];
    s += d * d;
  }
  s = blockReduce(s);
  if (threadIdx.x == 0) atomicAdd(acc, s * coef);
}

__global__ __launch_bounds__(256) void k_lossS(const float* __restrict__ Sa, const float* __restrict__ Sb,
                                               const int* __restrict__ cnt, float target, float coef,
                                               float* __restrict__ acc) {
  int c = blockIdx.x;
  int n = min(cnt[c], CAP);
  float s = 0.f;
  for (int p = threadIdx.x; p < n * n; p += 256) {
    int i = p / n, j = p % n;
    size_t o = ((size_t)c * CAP + i) * CAP + j;
    float d = Sb ? (Sa[o] - Sb[o]) : (Sa[o] - target);
    s += d * d;
  }
  s = blockReduce(s);
  if (threadIdx.x == 0) atomicAdd(acc, s * coef);
}

__global__ void k_final(const float* __restrict__ acc, float* __restrict__ out) {
  if (threadIdx.x == 0) out[0] = acc[0];
}

// ---------------- host ----------------
extern "C" void kernel_launch(void* const* d_in, const int* in_sizes, int n_in,
                              void* d_out, int out_size, void* d_ws, size_t ws_size,
                              hipStream_t stream) {
  const float* feats = (const float*)d_in[0];
  const int* labels = (const int*)d_in[1];
  const float* fc1 = (const float*)d_in[2];
  const float* fc2 = (const float*)d_in[3];
  const float* gamma = (const float*)d_in[4];
  const float* beta = (const float*)d_in[5];
  const float* proj = (const float*)d_in[6];
  float* out = (float*)d_out;

  char* w = (char*)d_ws;
  auto alloc = [&](size_t bytes) { char* p = w; w += (bytes + 255) & ~(size_t)255; return p; };
  float* bufA = (float*)alloc((size_t)NROWS * DIM * 4);
  float* bufB = (float*)alloc((size_t)NROWS * DIM * 4);
  unsigned short* Gpb = (unsigned short*)alloc((size_t)NROWS * DIM * 2);
  unsigned short* actb = (unsigned short*)alloc((size_t)NROWS * DIM * 2);
  unsigned short* W1b = (unsigned short*)alloc((size_t)3 * DIM * DIM * 2);
  unsigned short* W2b = (unsigned short*)alloc((size_t)3 * DIM * DIM * 2);
  unsigned short* Pjb = (unsigned short*)alloc((size_t)PD * DIM * 2);
  float* sim  = (float*)alloc((size_t)NCLS * CAP * CAP * 4);
  float* S0   = (float*)alloc((size_t)NCLS * CAP * CAP * 4);
  float* S1   = (float*)alloc((size_t)NCLS * CAP * CAP * 4);
  float* PA   = (float*)alloc((size_t)NROWS * PD * 4);
  float* PB   = (float*)alloc((size_t)NROWS * PD * 4);
  float* invn = (float*)alloc(NROWS * 4);
  float* dinv = (float*)alloc(NCLS * CAP * 4);
  float* part = (float*)alloc((size_t)(NROWS / 32) * 1024 * 4);
  float* bnsc = (float*)alloc(2 * DIM * 4);
  float* acc  = (float*)alloc(256);
  int* cnt  = (int*)alloc(NCLS * 4);
  int* offc = (int*)alloc((NCLS + 1) * 4);
  int* perm = (int*)alloc(NROWS * 4);
  int* clsp = (int*)alloc(NROWS * 4);
  int* t8   = (int*)alloc(NROWS * 8 * 4);
  int* chunkCnt  = (int*)alloc(16 * NCLS * 4);
  int* chunkBase = (int*)alloc(16 * NCLS * 4);

  const float LAM_K = 64.f, LAM_Z = 16.f, SIGMA = 0.99f;
  const float cK = LAM_K / ((float)NROWS * (float)NROWS);
  const float cZ = LAM_Z / ((float)NROWS * (float)PD);
  const float cI = 1.f / ((float)NROWS * (float)NROWS);

  hipLaunchKernelGGL(k_zerof, dim3(1), dim3(64), 0, stream, acc, 4);
  hipLaunchKernelGGL(k_hist, dim3(16), dim3(256), 0, stream, labels, chunkCnt);
  hipLaunchKernelGGL(k_scan, dim3(1), dim3(64), 0, stream, chunkCnt, cnt, offc, chunkBase);
  hipLaunchKernelGGL(k_scatter, dim3(16), dim3(256), 0, stream, labels, chunkBase, perm, clsp);
  // all weights -> bf16 once
  hipLaunchKernelGGL(k_tobf16, dim3((3 * DIM * DIM / 4 + 255) / 256), dim3(256), 0, stream,
                     (const float4*)fc1, (ushort4*)W1b, 3 * DIM * DIM / 4);
  hipLaunchKernelGGL(k_tobf16, dim3((3 * DIM * DIM / 4 + 255) / 256), dim3(256), 0, stream,
                     (const float4*)fc2, (ushort4*)W2b, 3 * DIM * DIM / 4);
  hipLaunchKernelGGL(k_tobf16, dim3((PD * DIM / 4 + 255) / 256), dim3(256), 0, stream,
                     (const float4*)proj, (ushort4*)Pjb, PD * DIM / 4);

  float* Sbuf[2] = {S0, S1};
  float* Pbuf[2] = {PA, PB};

  for (int l = 0; l < 3; ++l) {
    const float* G = feats + (size_t)l * NROWS * DIM;
    float alpha = 1.0f + 0.1f * l;
    float* Scur = Sbuf[l & 1];
    float* Sprev = Sbuf[(l & 1) ^ 1];
    float* Pcur = Pbuf[l & 1];
    float* Pprev = Pbuf[(l & 1) ^ 1];

    hipLaunchKernelGGL(k_prep, dim3(NROWS), dim3(128), 0, stream, G, perm, Gpb, invn);
    hipLaunchKernelGGL(k_sim, dim3(16, NCLS), dim3(256), 0, stream, Gpb, invn, cnt, offc, sim);
    hipLaunchKernelGGL(k_topk, dim3(NROWS / 64), dim3(64), 0, stream, sim, cnt, offc, clsp, t8);
    hipLaunchKernelGGL(k_buildS1, dim3(NCLS, CAP / 32), dim3(256), 0, stream, sim, cnt, offc, t8, alpha, Scur, dinv);
    hipLaunchKernelGGL(k_buildS2, dim3(NCLS, CAP / 32), dim3(256), 0, stream, Scur, dinv, cnt);

    // T1 = Gp @ w1^T  (bf16 MFMA)
    hipLaunchKernelGGL(k_gemm_bf16, dim3(NROWS / 128, DIM / 64), dim3(256), 0, stream,
                       (const short*)Gpb, (const short*)(W1b + (size_t)l * DIM * DIM), bufA, DIM);
    // T2 = S @ T1 (fp32)
    hipLaunchKernelGGL(k_spmm2, dim3(NCLS, DIM / 64, CAP / 32), dim3(256), 0, stream, Scur, bufA,
                       (const float*)nullptr, (const int*)nullptr, bufB, (unsigned short*)nullptr, cnt, offc);
    // BN stats + relu -> bf16 T3
    hipLaunchKernelGGL(k_colstats, dim3(NROWS / 32), dim3(256), 0, stream, bufB, part);
    hipLaunchKernelGGL(k_bnfin, dim3(DIM / 64), dim3(64), 0, stream, part, gamma + (size_t)l * DIM, beta + (size_t)l * DIM, bnsc);
    hipLaunchKernelGGL(k_bnrelu, dim3(NROWS * DIM / 4 / 256), dim3(256), 0, stream,
                       (const float4*)bufB, bnsc, (ushort4*)actb);
    // T4 = T3 @ w2^T -> bufB
    hipLaunchKernelGGL(k_gemm_bf16, dim3(NROWS / 128, DIM / 64), dim3(256), 0, stream,
                       (const short*)actb, (const short*)(W2b + (size_t)l * DIM * DIM), bufB, DIM);
    // Z = S @ T4 + G (residual via perm) -> bf16 Zb (actb)
    hipLaunchKernelGGL(k_spmm2, dim3(NCLS, DIM / 64, CAP / 32), dim3(256), 0, stream, Scur, bufB,
                       G, perm, (float*)nullptr, actb, cnt, offc);
    // P = l2norm(Z @ proj^T)
    hipLaunchKernelGGL(k_gemm_bf16, dim3(NROWS / 128, PD / 64), dim3(256), 0, stream,
                       (const short*)actb, (const short*)Pjb, Pcur, PD);
    hipLaunchKernelGGL(k_rownormP, dim3(NROWS), dim3(192), 0, stream, Pcur);

    if (l >= 1) {
      hipLaunchKernelGGL(k_lossS, dim3(NCLS), dim3(256), 0, stream, Sprev, Scur, cnt, 0.f, cK, acc);
      hipLaunchKernelGGL(k_lossdiff, dim3(1024), dim3(256), 0, stream, Pprev, Pcur, NROWS * PD, cZ, acc);
    }
    if (l == 2) {
      hipLaunchKernelGGL(k_lossS, dim3(NCLS), dim3(256), 0, stream, Scur, (const float*)nullptr, cnt, SIGMA, cI, acc);
    }
  }
  hipLaunchKernelGGL(k_final, dim3(1), dim3(64), 0, stream, acc, out);
}

// Round 6
// 308.459 us; speedup vs baseline: 5.0752x; 1.7388x over previous
//
#include <hip/hip_runtime.h>
#include <math.h>

#define NROWS 4096
#define DIM   512
#define NCLS  64
#define CAP   128
#define PD    768
#define NL    3

typedef __attribute__((ext_vector_type(8))) short short8v;
typedef __attribute__((ext_vector_type(4))) float f32x4;

__device__ __forceinline__ unsigned short f2bf(float f) {
  unsigned u = __float_as_uint(f);
  unsigned r = (u + 0x7FFF + ((u >> 16) & 1)) >> 16;
  return (unsigned short)r;
}

__device__ __forceinline__ float waveReduce(float v) {
#pragma unroll
  for (int o = 32; o > 0; o >>= 1) v += __shfl_down(v, o);
  return v;
}

__device__ __forceinline__ float blockReduce(float v) {
  __shared__ float sh[4];
  int lane = threadIdx.x & 63, wv = threadIdx.x >> 6;
  v = waveReduce(v);
  if (lane == 0) sh[wv] = v;
  __syncthreads();
  float t = 0.f;
  if (threadIdx.x == 0) {
    int nw = (blockDim.x + 63) >> 6;
    for (int i = 0; i < nw; ++i) t += sh[i];
  }
  return t;
}

__global__ void k_zerof(float* p, int n) {
  for (int i = blockIdx.x * blockDim.x + threadIdx.x; i < n; i += gridDim.x * blockDim.x) p[i] = 0.f;
}

// ---------------- parallel stable bucketing ----------------
__global__ __launch_bounds__(256) void k_hist(const int* __restrict__ labels, int* __restrict__ chunkCnt) {
  __shared__ int h[NCLS];
  int t = threadIdx.x;
  if (t < NCLS) h[t] = 0;
  __syncthreads();
  atomicAdd(&h[labels[blockIdx.x * 256 + t]], 1);
  __syncthreads();
  if (t < NCLS) chunkCnt[blockIdx.x * NCLS + t] = h[t];
}

__global__ void k_scan(const int* __restrict__ chunkCnt, int* __restrict__ cnt,
                       int* __restrict__ off, int* __restrict__ chunkBase) {
  __shared__ int sc[NCLS];
  int c = threadIdx.x;  // 64 threads
  int tot = 0;
  for (int b = 0; b < 16; ++b) tot += chunkCnt[b * NCLS + c];
  cnt[c] = tot;
  sc[c] = tot;
  __syncthreads();
  if (c == 0) {
    int s = 0;
    for (int i = 0; i < NCLS; ++i) { int tv = sc[i]; sc[i] = s; s += tv; }
  }
  __syncthreads();
  int run = sc[c];
  off[c] = run;
  for (int b = 0; b < 16; ++b) { chunkBase[b * NCLS + c] = run; run += chunkCnt[b * NCLS + c]; }
  if (c == 0) off[NCLS] = NROWS;
}

__global__ __launch_bounds__(256) void k_scatter(const int* __restrict__ labels, const int* __restrict__ chunkBase,
                                                 int* __restrict__ perm, int* __restrict__ clsp) {
  __shared__ int lab[256];
  int t = threadIdx.x;
  int r = blockIdx.x * 256 + t;
  int c = labels[r];
  lab[t] = c;
  __syncthreads();
  int rank = 0;
  for (int j = 0; j < t; ++j) rank += (lab[j] == c);
  int pos = chunkBase[blockIdx.x * NCLS + c] + rank;
  perm[pos] = r;
  clsp[pos] = c;
}

// gathered bf16 copy + row inverse norms; z = layer
__global__ __launch_bounds__(128) void k_prep(const float* __restrict__ feats, const int* __restrict__ perm,
                                              unsigned short* __restrict__ Gpb, float* __restrict__ invn) {
  __shared__ float red[2];
  int l = blockIdx.y;
  const float* G = feats + (size_t)l * NROWS * DIM;
  unsigned short* Gp = Gpb + (size_t)l * NROWS * DIM;
  int row = blockIdx.x, t = threadIdx.x;
  const float4* src = (const float4*)(G + (size_t)perm[row] * DIM);
  float4 v = src[t];
  ushort4 b;
  b.x = f2bf(v.x); b.y = f2bf(v.y); b.z = f2bf(v.z); b.w = f2bf(v.w);
  *(ushort4*)(Gp + (size_t)row * DIM + t * 4) = b;
  float ss = v.x * v.x + v.y * v.y + v.z * v.z + v.w * v.w;
  ss = waveReduce(ss);
  if ((t & 63) == 0) red[t >> 6] = ss;
  __syncthreads();
  if (t == 0) invn[l * NROWS + row] = 1.f / fmaxf(sqrtf(red[0] + red[1]), 1e-12f);
}

__global__ void k_tobf16(const float4* __restrict__ src, ushort4* __restrict__ dst, int n4) {
  int i = blockIdx.x * blockDim.x + threadIdx.x;
  if (i < n4) {
    float4 v = src[i];
    ushort4 o;
    o.x = f2bf(v.x); o.y = f2bf(v.y); o.z = f2bf(v.z); o.w = f2bf(v.w);
    dst[i] = o;
  }
}

// per-class cosine-sim via bf16 MFMA: 32x32 tile per block, 4 waves = 4 quadrants; z = layer
__global__ __launch_bounds__(256) void k_sim(const unsigned short* __restrict__ Gpb,
                                             const float* __restrict__ invn,
                                             const int* __restrict__ cnt, const int* __restrict__ off,
                                             float* __restrict__ sim) {
  int l = blockIdx.z;
  const unsigned short* Gp = Gpb + (size_t)l * NROWS * DIM;
  const float* inv = invn + (size_t)l * NROWS;
  float* sm = sim + (size_t)l * NCLS * CAP * CAP;
  int c = blockIdx.y;
  int n = min(cnt[c], CAP);
  int ti = blockIdx.x >> 2, tj = blockIdx.x & 3;
  if (ti * 32 >= n || tj * 32 >= n) return;
  int base = off[c];
  __shared__ short As[32][40];
  __shared__ short Bs[32][40];
  const int t = threadIdx.x;
  const int lane = t & 63, wv = t >> 6;
  const int qi = wv >> 1, qj = wv & 1;
  const int fr = lane & 15, kg = lane >> 4;
  const int half = t >> 7, tt = t & 127;
  const int srow = tt >> 2, scol = (tt & 3) * 8;
  int gr = (half ? tj : ti) * 32 + srow;
  const unsigned short* ps = Gp + (size_t)(base + min(gr, n - 1)) * DIM + scol;
  short* dst = half ? &Bs[srow][scol] : &As[srow][scol];
  f32x4 acc = {};
  for (int k0 = 0; k0 < DIM; k0 += 32) {
    short8v v = *(const short8v*)(ps + k0);
    __syncthreads();
    *(short8v*)dst = v;
    __syncthreads();
    short8v af = *(const short8v*)&As[qi * 16 + fr][kg * 8];
    short8v bf = *(const short8v*)&Bs[qj * 16 + fr][kg * 8];
    acc = __builtin_amdgcn_mfma_f32_16x16x32_bf16(af, bf, acc, 0, 0, 0);
  }
  int gj = tj * 32 + qj * 16 + fr;
  int r0 = ti * 32 + qi * 16 + kg * 4;
  if (gj < n) {
    float sj = inv[base + gj];
#pragma unroll
    for (int r = 0; r < 4; ++r) {
      int gi = r0 + r;
      if (gi < n) {
        float v = acc[r] * inv[base + gi] * sj;
        v = fminf(fmaxf(v, -1.0f + 1e-8f), 1.0f - 1e-8f);
        sm[((size_t)c * CAP + gi) * CAP + gj] = v;
      }
    }
  }
}

// top-8 per row within class; y = layer
__global__ __launch_bounds__(64) void k_topk(const float* __restrict__ sim, const int* __restrict__ cnt,
                                             const int* __restrict__ off, const int* __restrict__ clsp,
                                             int* __restrict__ t8) {
  int l = blockIdx.y;
  const float* sm = sim + (size_t)l * NCLS * CAP * CAP;
  int* t8l = t8 + (size_t)l * NROWS * 8;
  int pr = blockIdx.x * 64 + threadIdx.x;
  if (pr >= NROWS) return;
  int c = clsp[pr];
  int n = min(cnt[c], CAP);
  int loc = pr - off[c];
  const float* row = sm + ((size_t)c * CAP + loc) * CAP;
  float bv[8]; int bi[8];
#pragma unroll
  for (int q = 0; q < 8; ++q) { bv[q] = -3e38f; bi[q] = -1; }
  for (int j = 0; j < n; ++j) {
    if (j == loc) continue;
    float v = row[j];
    if (v > bv[7]) {
      bv[7] = v; bi[7] = j;
#pragma unroll
      for (int q = 7; q > 0; --q) {
        if (bv[q] > bv[q - 1]) {
          float tv = bv[q]; bv[q] = bv[q - 1]; bv[q - 1] = tv;
          int tq = bi[q]; bi[q] = bi[q - 1]; bi[q - 1] = tq;
        }
      }
    }
  }
#pragma unroll
  for (int q = 0; q < 8; ++q) t8l[pr * 8 + q] = bi[q];
}

// ---- build S pass 1: masked weights + row degree -> dinv; z = layer ----
__global__ __launch_bounds__(256) void k_buildS1(const float* __restrict__ sim, const int* __restrict__ cnt,
                                                 const int* __restrict__ off, const int* __restrict__ t8,
                                                 float* __restrict__ S, float* __restrict__ dinv) {
  int l = blockIdx.z;
  float alpha = 1.0f + 0.1f * l;
  const float* sm = sim + (size_t)l * NCLS * CAP * CAP;
  float* Sl = S + (size_t)l * NCLS * CAP * CAP;
  const int* t8l = t8 + (size_t)l * NROWS * 8;
  float* dv = dinv + (size_t)l * NCLS * CAP;
  int c = blockIdx.x;
  int n = min(cnt[c], CAP);
  int i0 = blockIdx.y * 32;
  if (i0 >= n) return;
  int base = off[c];
  __shared__ int sh8[CAP * 8];
  for (int i = threadIdx.x; i < n * 8; i += 256) sh8[i] = t8l[base * 8 + i];
  __syncthreads();
  int r = threadIdx.x >> 3;
  int lj = threadIdx.x & 7;
  int i = i0 + r;
  float d = 0.f;
  if (i < n) {
    int my8[8];
#pragma unroll
    for (int q = 0; q < 8; ++q) my8[q] = sh8[i * 8 + q];
    const float* srow = sm + ((size_t)c * CAP + i) * CAP;
    float* wrow = Sl + ((size_t)c * CAP + i) * CAP;
    for (int j = lj; j < n; j += 8) {
      float w;
      if (j == i) w = 1e-6f;
      else {
        bool m = false;
#pragma unroll
        for (int q = 0; q < 8; ++q) m = m || (my8[q] == j) || (sh8[j * 8 + q] == i);
        w = m ? alpha * fmaxf(srow[j], 0.f) : 0.f;
      }
      wrow[j] = w;
      d += w;
    }
  }
  d += __shfl_xor(d, 1);
  d += __shfl_xor(d, 2);
  d += __shfl_xor(d, 4);
  if (lj == 0 && i < n) dv[c * CAP + i] = 1.f / sqrtf(fmaxf(d, 1e-8f));
}

// ---- build S pass 2: S[i][j] *= dinv_i * dinv_j; z = layer ----
__global__ __launch_bounds__(256) void k_buildS2(float* __restrict__ S, const float* __restrict__ dinv,
                                                 const int* __restrict__ cnt) {
  int l = blockIdx.z;
  float* Sl = S + (size_t)l * NCLS * CAP * CAP;
  const float* dv = dinv + (size_t)l * NCLS * CAP;
  int c = blockIdx.x;
  int n = min(cnt[c], CAP);
  int i0 = blockIdx.y * 32;
  if (i0 >= n) return;
  __shared__ float sd[CAP];
  for (int k = threadIdx.x; k < n; k += 256) sd[k] = dv[c * CAP + k];
  __syncthreads();
  for (int p = threadIdx.x; p < 32 * CAP; p += 256) {
    int r = p >> 7, j = p & (CAP - 1);
    int i = i0 + r;
    if (i < n && j < n)
      Sl[((size_t)c * CAP + i) * CAP + j] *= sd[i] * sd[j];
  }
}

// ------------- bf16 MFMA GEMM, layer-batched: C_l = A_l @ B_l^T -------------
__global__ __launch_bounds__(256) void k_gemm_bf16(const short* __restrict__ A, const short* __restrict__ B,
                                                   float* __restrict__ C, int N,
                                                   long sA, long sB, long sC) {
  int l = blockIdx.z;
  A += (size_t)l * sA; B += (size_t)l * sB; C += (size_t)l * sC;
  __shared__ short As[128][40];
  __shared__ short Bs[64][40];
  const int row0 = blockIdx.x * 128, col0 = blockIdx.y * 64;
  const int t = threadIdx.x;
  const int lane = t & 63, wv = t >> 6;
  const int fr = lane & 15, kg = lane >> 4;
  const int sra = t >> 1, ska = (t & 1) * 16;
  const int srb = t >> 2, skb = (t & 3) * 8;
  const short* pa = A + (size_t)(row0 + sra) * DIM + ska;
  const short* pb = B + (size_t)(col0 + srb) * DIM + skb;
  f32x4 acc[2][4] = {};
  for (int kt = 0; kt < DIM; kt += 32) {
    short8v a0 = *(const short8v*)(pa + kt);
    short8v a1 = *(const short8v*)(pa + kt + 8);
    short8v b0 = *(const short8v*)(pb + kt);
    __syncthreads();
    *(short8v*)&As[sra][ska] = a0;
    *(short8v*)&As[sra][ska + 8] = a1;
    *(short8v*)&Bs[srb][skb] = b0;
    __syncthreads();
    short8v af[2], bf[4];
#pragma unroll
    for (int i = 0; i < 2; ++i) af[i] = *(const short8v*)&As[wv * 32 + i * 16 + fr][kg * 8];
#pragma unroll
    for (int j = 0; j < 4; ++j) bf[j] = *(const short8v*)&Bs[j * 16 + fr][kg * 8];
#pragma unroll
    for (int i = 0; i < 2; ++i)
#pragma unroll
      for (int j = 0; j < 4; ++j)
        acc[i][j] = __builtin_amdgcn_mfma_f32_16x16x32_bf16(af[i], bf[j], acc[i][j], 0, 0, 0);
  }
#pragma unroll
  for (int i = 0; i < 2; ++i) {
    int r0 = row0 + wv * 32 + i * 16 + kg * 4;
#pragma unroll
    for (int j = 0; j < 4; ++j) {
      int cc = col0 + j * 16 + fr;
#pragma unroll
      for (int r = 0; r < 4; ++r)
        C[(size_t)(r0 + r) * N + cc] = acc[i][j][r];
    }
  }
}

// Y = S @ X (+ residual); z = layer*4 + rowchunk
__global__ __launch_bounds__(256) void k_spmm2(const float* __restrict__ S, const float* __restrict__ X,
                                               const float* __restrict__ Gfeat, const int* __restrict__ perm,
                                               float* __restrict__ Y, unsigned short* __restrict__ Yb,
                                               const int* __restrict__ cnt, const int* __restrict__ off) {
  int l = blockIdx.z >> 2;
  int zc = blockIdx.z & 3;
  const float* Sl = S + (size_t)l * NCLS * CAP * CAP;
  const float* Xl = X + (size_t)l * NROWS * DIM;
  const float* Gl = Gfeat ? Gfeat + (size_t)l * NROWS * DIM : (const float*)nullptr;
  float* Yl = Y ? Y + (size_t)l * NROWS * DIM : (float*)nullptr;
  unsigned short* Ybl = Yb ? Yb + (size_t)l * NROWS * DIM : (unsigned short*)nullptr;
  int c = blockIdx.x;
  int n = min(cnt[c], CAP);
  int i0 = zc * 32;
  if (i0 >= n) return;
  int base = off[c];
  int col = blockIdx.y * 64 + (threadIdx.x & 63);
  int ty = threadIdx.x >> 6;
  __shared__ float sS[32][CAP];
  for (int idx = threadIdx.x; idx < 32 * n; idx += 256) {
    int r = idx / n, j = idx - r * n;
    sS[r][j] = (i0 + r < n) ? Sl[((size_t)c * CAP + i0 + r) * CAP + j] : 0.f;
  }
  __syncthreads();
  float acc[8] = {0, 0, 0, 0, 0, 0, 0, 0};
  for (int j = 0; j < n; ++j) {
    float x = Xl[(size_t)(base + j) * DIM + col];
#pragma unroll
    for (int ii = 0; ii < 8; ++ii) acc[ii] += sS[ty * 8 + ii][j] * x;
  }
#pragma unroll
  for (int ii = 0; ii < 8; ++ii) {
    int r = i0 + ty * 8 + ii;
    if (r < n) {
      size_t o = (size_t)(base + r) * DIM + col;
      float v = acc[ii];
      if (Gl) v += Gl[(size_t)perm[base + r] * DIM + col];
      if (Ybl) Ybl[o] = f2bf(v);
      else Yl[o] = v;
    }
  }
}

#define PARTSZ (size_t)((NROWS / 32) * 1024)

// column partial sums / sumsq; y = layer
__global__ __launch_bounds__(256) void k_colstats(const float* __restrict__ X, float* __restrict__ part) {
  int l = blockIdx.y;
  const float* Xl = X + (size_t)l * NROWS * DIM;
  float* pl = part + (size_t)l * PARTSZ;
  int rb = blockIdx.x, t = threadIdx.x;
#pragma unroll
  for (int cp = 0; cp < 2; ++cp) {
    int col = cp * 256 + t;
    float s = 0.f, s2 = 0.f;
    for (int r = 0; r < 32; ++r) {
      float v = Xl[(size_t)(rb * 32 + r) * DIM + col];
      s += v; s2 += v * v;
    }
    pl[rb * 1024 + col] = s;
    pl[rb * 1024 + 512 + col] = s2;
  }
}

__global__ __launch_bounds__(64) void k_bnfin(const float* __restrict__ part, const float* __restrict__ gamma,
                                              const float* __restrict__ beta, float* __restrict__ sc) {
  int l = blockIdx.y;
  const float* pl = part + (size_t)l * PARTSZ;
  int k = blockIdx.x * 64 + threadIdx.x;
  float s = 0.f, s2 = 0.f;
  for (int b = 0; b < NROWS / 32; ++b) {
    s += pl[b * 1024 + k];
    s2 += pl[b * 1024 + 512 + k];
  }
  float m = s * (1.f / NROWS);
  float var = s2 * (1.f / NROWS) - m * m;
  float sg = gamma[l * DIM + k] / sqrtf(var + 1e-5f);
  sc[l * 2 * DIM + k] = sg;
  sc[l * 2 * DIM + DIM + k] = beta[l * DIM + k] - m * sg;
}

// BN+ReLU -> bf16; y = layer
__global__ __launch_bounds__(256) void k_bnrelu(const float4* __restrict__ X, const float* __restrict__ sc,
                                                ushort4* __restrict__ Yb) {
  int l = blockIdx.y;
  const float4* Xl = X + (size_t)l * (NROWS * DIM / 4);
  const float* scl = sc + (size_t)l * 2 * DIM;
  ushort4* Yl = Yb + (size_t)l * (NROWS * DIM / 4);
  int i = blockIdx.x * blockDim.x + threadIdx.x;
  int cb = (i * 4) & (DIM - 1);
  float4 v = Xl[i];
  ushort4 o;
  o.x = f2bf(fmaxf(v.x * scl[cb + 0] + scl[DIM + cb + 0], 0.f));
  o.y = f2bf(fmaxf(v.y * scl[cb + 1] + scl[DIM + cb + 1], 0.f));
  o.z = f2bf(fmaxf(v.z * scl[cb + 2] + scl[DIM + cb + 2], 0.f));
  o.w = f2bf(fmaxf(v.w * scl[cb + 3] + scl[DIM + cb + 3], 0.f));
  Yl[i] = o;
}

// row l2norm of P; y = layer
__global__ __launch_bounds__(192) void k_rownormP(float* __restrict__ P) {
  __shared__ float red[3];
  __shared__ float s_inv;
  int l = blockIdx.y;
  float* Pl = P + (size_t)l * NROWS * PD;
  int row = blockIdx.x, t = threadIdx.x;
  float4* p = (float4*)(Pl + (size_t)row * PD);
  float4 v = p[t];
  float ss = v.x * v.x + v.y * v.y + v.z * v.z + v.w * v.w;
  ss = waveReduce(ss);
  if ((t & 63) == 0) red[t >> 6] = ss;
  __syncthreads();
  if (t == 0) s_inv = 1.f / fmaxf(sqrtf(red[0] + red[1] + red[2]), 1e-12f);
  __syncthreads();
  float inv = s_inv;
  v.x *= inv; v.y *= inv; v.z *= inv; v.w *= inv;
  p[t] = v;
}

// loss_Z pairs: y in {0,1} -> (P[y], P[y+1])
__global__ __launch_bounds__(256) void k_lossdiff(const float* __restrict__ P, int n, float coef,
                                                  float* __restrict__ acc) {
  int y = blockIdx.y;
  const float* A = P + (size_t)y * NROWS * PD;
  const float* B = A + (size_t)NROWS * PD;
  float s = 0.f;
  for (int i = blockIdx.x * blockDim.x + threadIdx.x; i < n; i += gridDim.x * blockDim.x) {
    float d = A[i] - B[i];
    s += d * d;
  }
  s = blockReduce(s);
  if (threadIdx.x == 0) atomicAdd(acc, s * coef);
}

// loss_K / loss_idea: y in {0,1}: (S[y]-S[y+1])^2 * cK ; y==2: (S[2]-SIGMA)^2 * cI
__global__ __launch_bounds__(256) void k_lossS(const float* __restrict__ S, const int* __restrict__ cnt,
                                               float target, float cK, float cI,
                                               float* __restrict__ acc) {
  int y = blockIdx.y;
  const float* Sa = S + (size_t)y * NCLS * CAP * CAP * (y < 2 ? 1 : 1);
  const float* Sb = nullptr;
  float coef;
  if (y < 2) { Sb = Sa + (size_t)NCLS * CAP * CAP; coef = cK; }
  else { Sa = S + (size_t)2 * NCLS * CAP * CAP; coef = cI; }
  int c = blockIdx.x;
  int n = min(cnt[c], CAP);
  float s = 0.f;
  for (int p = threadIdx.x; p < CAP * CAP; p += 256) {
    int i = p >> 7, j = p & (CAP - 1);
    if (i < n && j < n) {
      size_t o = ((size_t)c * CAP + i) * CAP + j;
      float d = Sb ? (Sa[o] - Sb[o]) : (Sa[o] - target);
      s += d * d;
    }
  }
  s = blockReduce(s);
  if (threadIdx.x == 0) atomicAdd(acc, s * coef);
}

__global__ void k_final(const float* __restrict__ acc, float* __restrict__ out) {
  if (threadIdx.x == 0) out[0] = acc[0];
}

// ---------------- host ----------------
extern "C" void kernel_launch(void* const* d_in, const int* in_sizes, int n_in,
                              void* d_out, int out_size, void* d_ws, size_t ws_size,
                              hipStream_t stream) {
  const float* feats = (const float*)d_in[0];
  const int* labels = (const int*)d_in[1];
  const float* fc1 = (const float*)d_in[2];
  const float* fc2 = (const float*)d_in[3];
  const float* gamma = (const float*)d_in[4];
  const float* beta = (const float*)d_in[5];
  const float* proj = (const float*)d_in[6];
  float* out = (float*)d_out;

  char* w = (char*)d_ws;
  auto alloc = [&](size_t bytes) { char* p = w; w += (bytes + 255) & ~(size_t)255; return p; };
  float* bufA = (float*)alloc((size_t)NL * NROWS * DIM * 4);
  float* bufB = (float*)alloc((size_t)NL * NROWS * DIM * 4);
  unsigned short* Gpb = (unsigned short*)alloc((size_t)NL * NROWS * DIM * 2);
  unsigned short* actb = (unsigned short*)alloc((size_t)NL * NROWS * DIM * 2);
  unsigned short* W1b = (unsigned short*)alloc((size_t)NL * DIM * DIM * 2);
  unsigned short* W2b = (unsigned short*)alloc((size_t)NL * DIM * DIM * 2);
  unsigned short* Pjb = (unsigned short*)alloc((size_t)PD * DIM * 2);
  float* sim  = (float*)alloc((size_t)NL * NCLS * CAP * CAP * 4);
  float* S    = (float*)alloc((size_t)NL * NCLS * CAP * CAP * 4);
  float* P    = (float*)alloc((size_t)NL * NROWS * PD * 4);
  float* invn = (float*)alloc((size_t)NL * NROWS * 4);
  float* dinv = (float*)alloc((size_t)NL * NCLS * CAP * 4);
  float* part = (float*)alloc((size_t)NL * PARTSZ * 4);
  float* bnsc = (float*)alloc((size_t)NL * 2 * DIM * 4);
  float* acc  = (float*)alloc(256);
  int* cnt  = (int*)alloc(NCLS * 4);
  int* offc = (int*)alloc((NCLS + 1) * 4);
  int* perm = (int*)alloc(NROWS * 4);
  int* clsp = (int*)alloc(NROWS * 4);
  int* t8   = (int*)alloc((size_t)NL * NROWS * 8 * 4);
  int* chunkCnt  = (int*)alloc(16 * NCLS * 4);
  int* chunkBase = (int*)alloc(16 * NCLS * 4);

  const float LAM_K = 64.f, LAM_Z = 16.f, SIGMA = 0.99f;
  const float cK = LAM_K / ((float)NROWS * (float)NROWS);
  const float cZ = LAM_Z / ((float)NROWS * (float)PD);
  const float cI = 1.f / ((float)NROWS * (float)NROWS);
  const long sAct = (long)NROWS * DIM;   // bf16 activation stride
  const long sW = (long)DIM * DIM;

  hipLaunchKernelGGL(k_zerof, dim3(1), dim3(64), 0, stream, acc, 4);
  hipLaunchKernelGGL(k_hist, dim3(16), dim3(256), 0, stream, labels, chunkCnt);
  hipLaunchKernelGGL(k_scan, dim3(1), dim3(64), 0, stream, chunkCnt, cnt, offc, chunkBase);
  hipLaunchKernelGGL(k_scatter, dim3(16), dim3(256), 0, stream, labels, chunkBase, perm, clsp);
  hipLaunchKernelGGL(k_tobf16, dim3((NL * DIM * DIM / 4 + 255) / 256), dim3(256), 0, stream,
                     (const float4*)fc1, (ushort4*)W1b, NL * DIM * DIM / 4);
  hipLaunchKernelGGL(k_tobf16, dim3((NL * DIM * DIM / 4 + 255) / 256), dim3(256), 0, stream,
                     (const float4*)fc2, (ushort4*)W2b, NL * DIM * DIM / 4);
  hipLaunchKernelGGL(k_tobf16, dim3((PD * DIM / 4 + 255) / 256), dim3(256), 0, stream,
                     (const float4*)proj, (ushort4*)Pjb, PD * DIM / 4);

  // --- all layers batched ---
  hipLaunchKernelGGL(k_prep, dim3(NROWS, NL), dim3(128), 0, stream, feats, perm, Gpb, invn);
  hipLaunchKernelGGL(k_sim, dim3(16, NCLS, NL), dim3(256), 0, stream, Gpb, invn, cnt, offc, sim);
  hipLaunchKernelGGL(k_topk, dim3(NROWS / 64, NL), dim3(64), 0, stream, sim, cnt, offc, clsp, t8);
  hipLaunchKernelGGL(k_buildS1, dim3(NCLS, CAP / 32, NL), dim3(256), 0, stream, sim, cnt, offc, t8, S, dinv);
  hipLaunchKernelGGL(k_buildS2, dim3(NCLS, CAP / 32, NL), dim3(256), 0, stream, S, dinv, cnt);

  // T1 = Gp @ w1^T
  hipLaunchKernelGGL(k_gemm_bf16, dim3(NROWS / 128, DIM / 64, NL), dim3(256), 0, stream,
                     (const short*)Gpb, (const short*)W1b, bufA, DIM, sAct, sW, (long)NROWS * DIM);
  // T2 = S @ T1
  hipLaunchKernelGGL(k_spmm2, dim3(NCLS, DIM / 64, 4 * NL), dim3(256), 0, stream, S, bufA,
                     (const float*)nullptr, (const int*)nullptr, bufB, (unsigned short*)nullptr, cnt, offc);
  // BN stats + relu -> bf16 T3
  hipLaunchKernelGGL(k_colstats, dim3(NROWS / 32, NL), dim3(256), 0, stream, bufB, part);
  hipLaunchKernelGGL(k_bnfin, dim3(DIM / 64, NL), dim3(64), 0, stream, part, gamma, beta, bnsc);
  hipLaunchKernelGGL(k_bnrelu, dim3(NROWS * DIM / 4 / 256, NL), dim3(256), 0, stream,
                     (const float4*)bufB, bnsc, (ushort4*)actb);
  // T4 = T3 @ w2^T
  hipLaunchKernelGGL(k_gemm_bf16, dim3(NROWS / 128, DIM / 64, NL), dim3(256), 0, stream,
                     (const short*)actb, (const short*)W2b, bufB, DIM, sAct, sW, (long)NROWS * DIM);
  // Z = S @ T4 + G -> bf16 (actb)
  hipLaunchKernelGGL(k_spmm2, dim3(NCLS, DIM / 64, 4 * NL), dim3(256), 0, stream, S, bufB,
                     feats, perm, (float*)nullptr, actb, cnt, offc);
  // P = l2norm(Z @ proj^T)
  hipLaunchKernelGGL(k_gemm_bf16, dim3(NROWS / 128, PD / 64, NL), dim3(256), 0, stream,
                     (const short*)actb, (const short*)Pjb, P, PD, sAct, 0L, (long)NROWS * PD);
  hipLaunchKernelGGL(k_rownormP, dim3(NROWS, NL), dim3(192), 0, stream, P);

  // losses
  hipLaunchKernelGGL(k_lossS, dim3(NCLS, 3), dim3(256), 0, stream, S, cnt, SIGMA, cK, cI, acc);
  hipLaunchKernelGGL(k_lossdiff, dim3(512, 2), dim3(256), 0, stream, P, NROWS * PD, cZ, acc);

  hipLaunchKernelGGL(k_final, dim3(1), dim3(64), 0, stream, acc, out);
}

// Round 7
// 278.096 us; speedup vs baseline: 5.6293x; 1.1092x over previous
//
#include <hip/hip_runtime.h>
#include <math.h>

#define NROWS 4096
#define DIM   512
#define NCLS  64
#define CAP   128
#define PD    768
#define NL    3

typedef __attribute__((ext_vector_type(8))) short short8v;
typedef __attribute__((ext_vector_type(4))) float f32x4;

__device__ __forceinline__ unsigned short f2bf(float f) {
  unsigned u = __float_as_uint(f);
  unsigned r = (u + 0x7FFF + ((u >> 16) & 1)) >> 16;
  return (unsigned short)r;
}

__device__ __forceinline__ float waveReduce(float v) {
#pragma unroll
  for (int o = 32; o > 0; o >>= 1) v += __shfl_down(v, o);
  return v;
}

__device__ __forceinline__ float blockReduce(float v) {
  __shared__ float sh[4];
  int lane = threadIdx.x & 63, wv = threadIdx.x >> 6;
  v = waveReduce(v);
  if (lane == 0) sh[wv] = v;
  __syncthreads();
  float t = 0.f;
  if (threadIdx.x == 0) {
    int nw = (blockDim.x + 63) >> 6;
    for (int i = 0; i < nw; ++i) t += sh[i];
  }
  return t;
}

__global__ void k_zerof(float* p, int n) {
  for (int i = blockIdx.x * blockDim.x + threadIdx.x; i < n; i += gridDim.x * blockDim.x) p[i] = 0.f;
}

// ---------------- parallel stable bucketing ----------------
__global__ __launch_bounds__(256) void k_hist(const int* __restrict__ labels, int* __restrict__ chunkCnt) {
  __shared__ int h[NCLS];
  int t = threadIdx.x;
  if (t < NCLS) h[t] = 0;
  __syncthreads();
  atomicAdd(&h[labels[blockIdx.x * 256 + t]], 1);
  __syncthreads();
  if (t < NCLS) chunkCnt[blockIdx.x * NCLS + t] = h[t];
}

__global__ void k_scan(const int* __restrict__ chunkCnt, int* __restrict__ cnt,
                       int* __restrict__ off, int* __restrict__ chunkBase) {
  __shared__ int sc[NCLS];
  int c = threadIdx.x;  // 64 threads
  int tot = 0;
  for (int b = 0; b < 16; ++b) tot += chunkCnt[b * NCLS + c];
  cnt[c] = tot;
  sc[c] = tot;
  __syncthreads();
  if (c == 0) {
    int s = 0;
    for (int i = 0; i < NCLS; ++i) { int tv = sc[i]; sc[i] = s; s += tv; }
  }
  __syncthreads();
  int run = sc[c];
  off[c] = run;
  for (int b = 0; b < 16; ++b) { chunkBase[b * NCLS + c] = run; run += chunkCnt[b * NCLS + c]; }
  if (c == 0) off[NCLS] = NROWS;
}

__global__ __launch_bounds__(256) void k_scatter(const int* __restrict__ labels, const int* __restrict__ chunkBase,
                                                 int* __restrict__ perm, int* __restrict__ clsp) {
  __shared__ int lab[256];
  int t = threadIdx.x;
  int r = blockIdx.x * 256 + t;
  int c = labels[r];
  lab[t] = c;
  __syncthreads();
  int rank = 0;
  for (int j = 0; j < t; ++j) rank += (lab[j] == c);
  int pos = chunkBase[blockIdx.x * NCLS + c] + rank;
  perm[pos] = r;
  clsp[pos] = c;
}

// gathered bf16 copy + row inverse norms; z = layer
__global__ __launch_bounds__(128) void k_prep(const float* __restrict__ feats, const int* __restrict__ perm,
                                              unsigned short* __restrict__ Gpb, float* __restrict__ invn) {
  __shared__ float red[2];
  int l = blockIdx.y;
  const float* G = feats + (size_t)l * NROWS * DIM;
  unsigned short* Gp = Gpb + (size_t)l * NROWS * DIM;
  int row = blockIdx.x, t = threadIdx.x;
  const float4* src = (const float4*)(G + (size_t)perm[row] * DIM);
  float4 v = src[t];
  ushort4 b;
  b.x = f2bf(v.x); b.y = f2bf(v.y); b.z = f2bf(v.z); b.w = f2bf(v.w);
  *(ushort4*)(Gp + (size_t)row * DIM + t * 4) = b;
  float ss = v.x * v.x + v.y * v.y + v.z * v.z + v.w * v.w;
  ss = waveReduce(ss);
  if ((t & 63) == 0) red[t >> 6] = ss;
  __syncthreads();
  if (t == 0) invn[l * NROWS + row] = 1.f / fmaxf(sqrtf(red[0] + red[1]), 1e-12f);
}

__global__ void k_tobf16(const float4* __restrict__ src, ushort4* __restrict__ dst, int n4) {
  int i = blockIdx.x * blockDim.x + threadIdx.x;
  if (i < n4) {
    float4 v = src[i];
    ushort4 o;
    o.x = f2bf(v.x); o.y = f2bf(v.y); o.z = f2bf(v.z); o.w = f2bf(v.w);
    dst[i] = o;
  }
}

// per-class cosine-sim via bf16 MFMA: 32x32 tile per block; z = layer
__global__ __launch_bounds__(256) void k_sim(const unsigned short* __restrict__ Gpb,
                                             const float* __restrict__ invn,
                                             const int* __restrict__ cnt, const int* __restrict__ off,
                                             float* __restrict__ sim) {
  int l = blockIdx.z;
  const unsigned short* Gp = Gpb + (size_t)l * NROWS * DIM;
  const float* inv = invn + (size_t)l * NROWS;
  float* sm = sim + (size_t)l * NCLS * CAP * CAP;
  int c = blockIdx.y;
  int n = min(cnt[c], CAP);
  int ti = blockIdx.x >> 2, tj = blockIdx.x & 3;
  if (ti * 32 >= n || tj * 32 >= n) return;
  int base = off[c];
  __shared__ short As[32][40];
  __shared__ short Bs[32][40];
  const int t = threadIdx.x;
  const int lane = t & 63, wv = t >> 6;
  const int qi = wv >> 1, qj = wv & 1;
  const int fr = lane & 15, kg = lane >> 4;
  const int half = t >> 7, tt = t & 127;
  const int srow = tt >> 2, scol = (tt & 3) * 8;
  int gr = (half ? tj : ti) * 32 + srow;
  const unsigned short* ps = Gp + (size_t)(base + min(gr, n - 1)) * DIM + scol;
  short* dst = half ? &Bs[srow][scol] : &As[srow][scol];
  f32x4 acc = {};
  for (int k0 = 0; k0 < DIM; k0 += 32) {
    short8v v = *(const short8v*)(ps + k0);
    __syncthreads();
    *(short8v*)dst = v;
    __syncthreads();
    short8v af = *(const short8v*)&As[qi * 16 + fr][kg * 8];
    short8v bf = *(const short8v*)&Bs[qj * 16 + fr][kg * 8];
    acc = __builtin_amdgcn_mfma_f32_16x16x32_bf16(af, bf, acc, 0, 0, 0);
  }
  int gj = tj * 32 + qj * 16 + fr;
  int r0 = ti * 32 + qi * 16 + kg * 4;
  if (gj < n) {
    float sj = inv[base + gj];
#pragma unroll
    for (int r = 0; r < 4; ++r) {
      int gi = r0 + r;
      if (gi < n) {
        float v = acc[r] * inv[base + gi] * sj;
        v = fminf(fmaxf(v, -1.0f + 1e-8f), 1.0f - 1e-8f);
        sm[((size_t)c * CAP + gi) * CAP + gj] = v;
      }
    }
  }
}

// top-8 per row within class; y = layer
__global__ __launch_bounds__(64) void k_topk(const float* __restrict__ sim, const int* __restrict__ cnt,
                                             const int* __restrict__ off, const int* __restrict__ clsp,
                                             int* __restrict__ t8) {
  int l = blockIdx.y;
  const float* sm = sim + (size_t)l * NCLS * CAP * CAP;
  int* t8l = t8 + (size_t)l * NROWS * 8;
  int pr = blockIdx.x * 64 + threadIdx.x;
  if (pr >= NROWS) return;
  int c = clsp[pr];
  int n = min(cnt[c], CAP);
  int loc = pr - off[c];
  const float* row = sm + ((size_t)c * CAP + loc) * CAP;
  float bv[8]; int bi[8];
#pragma unroll
  for (int q = 0; q < 8; ++q) { bv[q] = -3e38f; bi[q] = -1; }
  for (int j = 0; j < n; ++j) {
    if (j == loc) continue;
    float v = row[j];
    if (v > bv[7]) {
      bv[7] = v; bi[7] = j;
#pragma unroll
      for (int q = 7; q > 0; --q) {
        if (bv[q] > bv[q - 1]) {
          float tv = bv[q]; bv[q] = bv[q - 1]; bv[q - 1] = tv;
          int tq = bi[q]; bi[q] = bi[q - 1]; bi[q - 1] = tq;
        }
      }
    }
  }
#pragma unroll
  for (int q = 0; q < 8; ++q) t8l[pr * 8 + q] = bi[q];
}

// ---- build S pass 1: masked weights + row degree -> dinv; z = layer ----
__global__ __launch_bounds__(256) void k_buildS1(const float* __restrict__ sim, const int* __restrict__ cnt,
                                                 const int* __restrict__ off, const int* __restrict__ t8,
                                                 float* __restrict__ S, float* __restrict__ dinv) {
  int l = blockIdx.z;
  float alpha = 1.0f + 0.1f * l;
  const float* sm = sim + (size_t)l * NCLS * CAP * CAP;
  float* Sl = S + (size_t)l * NCLS * CAP * CAP;
  const int* t8l = t8 + (size_t)l * NROWS * 8;
  float* dv = dinv + (size_t)l * NCLS * CAP;
  int c = blockIdx.x;
  int n = min(cnt[c], CAP);
  int i0 = blockIdx.y * 32;
  if (i0 >= n) return;
  int base = off[c];
  __shared__ int sh8[CAP * 8];
  for (int i = threadIdx.x; i < n * 8; i += 256) sh8[i] = t8l[base * 8 + i];
  __syncthreads();
  int r = threadIdx.x >> 3;
  int lj = threadIdx.x & 7;
  int i = i0 + r;
  float d = 0.f;
  if (i < n) {
    int my8[8];
#pragma unroll
    for (int q = 0; q < 8; ++q) my8[q] = sh8[i * 8 + q];
    const float* srow = sm + ((size_t)c * CAP + i) * CAP;
    float* wrow = Sl + ((size_t)c * CAP + i) * CAP;
    for (int j = lj; j < n; j += 8) {
      float w;
      if (j == i) w = 1e-6f;
      else {
        bool m = false;
#pragma unroll
        for (int q = 0; q < 8; ++q) m = m || (my8[q] == j) || (sh8[j * 8 + q] == i);
        w = m ? alpha * fmaxf(srow[j], 0.f) : 0.f;
      }
      wrow[j] = w;
      d += w;
    }
  }
  d += __shfl_xor(d, 1);
  d += __shfl_xor(d, 2);
  d += __shfl_xor(d, 4);
  if (lj == 0 && i < n) dv[c * CAP + i] = 1.f / sqrtf(fmaxf(d, 1e-8f));
}

// ---- build S pass 2: S[i][j] *= dinv_i * dinv_j; z = layer ----
__global__ __launch_bounds__(256) void k_buildS2(float* __restrict__ S, const float* __restrict__ dinv,
                                                 const int* __restrict__ cnt) {
  int l = blockIdx.z;
  float* Sl = S + (size_t)l * NCLS * CAP * CAP;
  const float* dv = dinv + (size_t)l * NCLS * CAP;
  int c = blockIdx.x;
  int n = min(cnt[c], CAP);
  int i0 = blockIdx.y * 32;
  if (i0 >= n) return;
  __shared__ float sd[CAP];
  for (int k = threadIdx.x; k < n; k += 256) sd[k] = dv[c * CAP + k];
  __syncthreads();
  for (int p = threadIdx.x; p < 32 * CAP; p += 256) {
    int r = p >> 7, j = p & (CAP - 1);
    int i = i0 + r;
    if (i < n && j < n)
      Sl[((size_t)c * CAP + i) * CAP + j] *= sd[i] * sd[j];
  }
}

// ------------- bf16 MFMA GEMM, layer-batched: C_l = A_l @ B_l^T -------------
__global__ __launch_bounds__(256) void k_gemm_bf16(const short* __restrict__ A, const short* __restrict__ B,
                                                   float* __restrict__ C, int N,
                                                   long sA, long sB, long sC) {
  int l = blockIdx.z;
  A += (size_t)l * sA; B += (size_t)l * sB; C += (size_t)l * sC;
  __shared__ short As[128][40];
  __shared__ short Bs[64][40];
  const int row0 = blockIdx.x * 128, col0 = blockIdx.y * 64;
  const int t = threadIdx.x;
  const int lane = t & 63, wv = t >> 6;
  const int fr = lane & 15, kg = lane >> 4;
  const int sra = t >> 1, ska = (t & 1) * 16;
  const int srb = t >> 2, skb = (t & 3) * 8;
  const short* pa = A + (size_t)(row0 + sra) * DIM + ska;
  const short* pb = B + (size_t)(col0 + srb) * DIM + skb;
  f32x4 acc[2][4] = {};
  for (int kt = 0; kt < DIM; kt += 32) {
    short8v a0 = *(const short8v*)(pa + kt);
    short8v a1 = *(const short8v*)(pa + kt + 8);
    short8v b0 = *(const short8v*)(pb + kt);
    __syncthreads();
    *(short8v*)&As[sra][ska] = a0;
    *(short8v*)&As[sra][ska + 8] = a1;
    *(short8v*)&Bs[srb][skb] = b0;
    __syncthreads();
    short8v af[2], bf[4];
#pragma unroll
    for (int i = 0; i < 2; ++i) af[i] = *(const short8v*)&As[wv * 32 + i * 16 + fr][kg * 8];
#pragma unroll
    for (int j = 0; j < 4; ++j) bf[j] = *(const short8v*)&Bs[j * 16 + fr][kg * 8];
#pragma unroll
    for (int i = 0; i < 2; ++i)
#pragma unroll
      for (int j = 0; j < 4; ++j)
        acc[i][j] = __builtin_amdgcn_mfma_f32_16x16x32_bf16(af[i], bf[j], acc[i][j], 0, 0, 0);
  }
#pragma unroll
  for (int i = 0; i < 2; ++i) {
    int r0 = row0 + wv * 32 + i * 16 + kg * 4;
#pragma unroll
    for (int j = 0; j < 4; ++j) {
      int cc = col0 + j * 16 + fr;
#pragma unroll
      for (int r = 0; r < 4; ++r)
        C[(size_t)(r0 + r) * N + cc] = acc[i][j][r];
    }
  }
}

// Y = S @ X (+ residual); z = layer*4 + rowchunk; each thread: 8 rows x 4 cols (float4)
__global__ __launch_bounds__(256) void k_spmm4(const float* __restrict__ S, const float* __restrict__ X,
                                               const float* __restrict__ Gfeat, const int* __restrict__ perm,
                                               float* __restrict__ Y, unsigned short* __restrict__ Yb,
                                               const int* __restrict__ cnt, const int* __restrict__ off) {
  int l = blockIdx.z >> 2;
  int zc = blockIdx.z & 3;
  const float* Sl = S + (size_t)l * NCLS * CAP * CAP;
  const float4* X4 = (const float4*)(X + (size_t)l * NROWS * DIM);
  const float4* G4 = Gfeat ? (const float4*)(Gfeat + (size_t)l * NROWS * DIM) : (const float4*)nullptr;
  float4* Y4 = Y ? (float4*)(Y + (size_t)l * NROWS * DIM) : (float4*)nullptr;
  ushort4* Yb4 = Yb ? (ushort4*)(Yb + (size_t)l * NROWS * DIM) : (ushort4*)nullptr;
  int c = blockIdx.x;
  int n = min(cnt[c], CAP);
  int i0 = zc * 32;
  if (i0 >= n) return;
  int base = off[c];
  int col4 = blockIdx.y * 64 + (threadIdx.x & 63);  // float4 index within row (row = 128 float4)
  int ty = threadIdx.x >> 6;                        // 4 groups x 8 rows
  __shared__ float sS[32][CAP];
  for (int idx = threadIdx.x; idx < 32 * n; idx += 256) {
    int r = idx / n, j = idx - r * n;
    sS[r][j] = (i0 + r < n) ? Sl[((size_t)c * CAP + i0 + r) * CAP + j] : 0.f;
  }
  __syncthreads();
  float4 acc[8];
#pragma unroll
  for (int ii = 0; ii < 8; ++ii) acc[ii] = make_float4(0.f, 0.f, 0.f, 0.f);
  for (int j = 0; j < n; ++j) {
    float4 x = X4[(size_t)(base + j) * 128 + col4];
#pragma unroll
    for (int ii = 0; ii < 8; ++ii) {
      float s = sS[ty * 8 + ii][j];
      acc[ii].x += s * x.x;
      acc[ii].y += s * x.y;
      acc[ii].z += s * x.z;
      acc[ii].w += s * x.w;
    }
  }
#pragma unroll
  for (int ii = 0; ii < 8; ++ii) {
    int r = i0 + ty * 8 + ii;
    if (r < n) {
      size_t o = (size_t)(base + r) * 128 + col4;
      float4 v = acc[ii];
      if (G4) {
        float4 g = G4[(size_t)perm[base + r] * 128 + col4];
        v.x += g.x; v.y += g.y; v.z += g.z; v.w += g.w;
      }
      if (Yb4) {
        ushort4 ob;
        ob.x = f2bf(v.x); ob.y = f2bf(v.y); ob.z = f2bf(v.z); ob.w = f2bf(v.w);
        Yb4[o] = ob;
      } else {
        Y4[o] = v;
      }
    }
  }
}

#define PARTSZ (size_t)((NROWS / 32) * 1024)

// column partial sums / sumsq; y = layer
__global__ __launch_bounds__(256) void k_colstats(const float* __restrict__ X, float* __restrict__ part) {
  int l = blockIdx.y;
  const float* Xl = X + (size_t)l * NROWS * DIM;
  float* pl = part + (size_t)l * PARTSZ;
  int rb = blockIdx.x, t = threadIdx.x;
#pragma unroll
  for (int cp = 0; cp < 2; ++cp) {
    int col = cp * 256 + t;
    float s = 0.f, s2 = 0.f;
    for (int r = 0; r < 32; ++r) {
      float v = Xl[(size_t)(rb * 32 + r) * DIM + col];
      s += v; s2 += v * v;
    }
    pl[rb * 1024 + col] = s;
    pl[rb * 1024 + 512 + col] = s2;
  }
}

__global__ __launch_bounds__(64) void k_bnfin(const float* __restrict__ part, const float* __restrict__ gamma,
                                              const float* __restrict__ beta, float* __restrict__ sc) {
  int l = blockIdx.y;
  const float* pl = part + (size_t)l * PARTSZ;
  int k = blockIdx.x * 64 + threadIdx.x;
  float s = 0.f, s2 = 0.f;
  for (int b = 0; b < NROWS / 32; ++b) {
    s += pl[b * 1024 + k];
    s2 += pl[b * 1024 + 512 + k];
  }
  float m = s * (1.f / NROWS);
  float var = s2 * (1.f / NROWS) - m * m;
  float sg = gamma[l * DIM + k] / sqrtf(var + 1e-5f);
  sc[l * 2 * DIM + k] = sg;
  sc[l * 2 * DIM + DIM + k] = beta[l * DIM + k] - m * sg;
}

// BN+ReLU -> bf16; y = layer
__global__ __launch_bounds__(256) void k_bnrelu(const float4* __restrict__ X, const float* __restrict__ sc,
                                                ushort4* __restrict__ Yb) {
  int l = blockIdx.y;
  const float4* Xl = X + (size_t)l * (NROWS * DIM / 4);
  const float* scl = sc + (size_t)l * 2 * DIM;
  ushort4* Yl = Yb + (size_t)l * (NROWS * DIM / 4);
  int i = blockIdx.x * blockDim.x + threadIdx.x;
  int cb = (i * 4) & (DIM - 1);
  float4 v = Xl[i];
  ushort4 o;
  o.x = f2bf(fmaxf(v.x * scl[cb + 0] + scl[DIM + cb + 0], 0.f));
  o.y = f2bf(fmaxf(v.y * scl[cb + 1] + scl[DIM + cb + 1], 0.f));
  o.z = f2bf(fmaxf(v.z * scl[cb + 2] + scl[DIM + cb + 2], 0.f));
  o.w = f2bf(fmaxf(v.w * scl[cb + 3] + scl[DIM + cb + 3], 0.f));
  Yl[i] = o;
}

// row l2norm of P; y = layer
__global__ __launch_bounds__(192) void k_rownormP(float* __restrict__ P) {
  __shared__ float red[3];
  __shared__ float s_inv;
  int l = blockIdx.y;
  float* Pl = P + (size_t)l * NROWS * PD;
  int row = blockIdx.x, t = threadIdx.x;
  float4* p = (float4*)(Pl + (size_t)row * PD);
  float4 v = p[t];
  float ss = v.x * v.x + v.y * v.y + v.z * v.z + v.w * v.w;
  ss = waveReduce(ss);
  if ((t & 63) == 0) red[t >> 6] = ss;
  __syncthreads();
  if (t == 0) s_inv = 1.f / fmaxf(sqrtf(red[0] + red[1] + red[2]), 1e-12f);
  __syncthreads();
  float inv = s_inv;
  v.x *= inv; v.y *= inv; v.z *= inv; v.w *= inv;
  p[t] = v;
}

// loss_Z pairs: y in {0,1} -> (P[y], P[y+1])
__global__ __launch_bounds__(256) void k_lossdiff(const float* __restrict__ P, int n, float coef,
                                                  float* __restrict__ acc) {
  int y = blockIdx.y;
  const float* A = P + (size_t)y * NROWS * PD;
  const float* B = A + (size_t)NROWS * PD;
  float s = 0.f;
  for (int i = blockIdx.x * blockDim.x + threadIdx.x; i < n; i += gridDim.x * blockDim.x) {
    float d = A[i] - B[i];
    s += d * d;
  }
  s = blockReduce(s);
  if (threadIdx.x == 0) atomicAdd(acc, s * coef);
}

// loss_K / loss_idea
__global__ __launch_bounds__(256) void k_lossS(const float* __restrict__ S, const int* __restrict__ cnt,
                                               float target, float cK, float cI,
                                               float* __restrict__ acc) {
  int y = blockIdx.y;
  const float* Sa = S + (size_t)y * NCLS * CAP * CAP;
  const float* Sb = nullptr;
  float coef;
  if (y < 2) { Sb = Sa + (size_t)NCLS * CAP * CAP; coef = cK; }
  else { Sa = S + (size_t)2 * NCLS * CAP * CAP; coef = cI; }
  int c = blockIdx.x;
  int n = min(cnt[c], CAP);
  float s = 0.f;
  for (int p = threadIdx.x; p < CAP * CAP; p += 256) {
    int i = p >> 7, j = p & (CAP - 1);
    if (i < n && j < n) {
      size_t o = ((size_t)c * CAP + i) * CAP + j;
      float d = Sb ? (Sa[o] - Sb[o]) : (Sa[o] - target);
      s += d * d;
    }
  }
  s = blockReduce(s);
  if (threadIdx.x == 0) atomicAdd(acc, s * coef);
}

__global__ void k_final(const float* __restrict__ acc, float* __restrict__ out) {
  if (threadIdx.x == 0) out[0] = acc[0];
}

// ---------------- host ----------------
extern "C" void kernel_launch(void* const* d_in, const int* in_sizes, int n_in,
                              void* d_out, int out_size, void* d_ws, size_t ws_size,
                              hipStream_t stream) {
  const float* feats = (const float*)d_in[0];
  const int* labels = (const int*)d_in[1];
  const float* fc1 = (const float*)d_in[2];
  const float* fc2 = (const float*)d_in[3];
  const float* gamma = (const float*)d_in[4];
  const float* beta = (const float*)d_in[5];
  const float* proj = (const float*)d_in[6];
  float* out = (float*)d_out;

  char* w = (char*)d_ws;
  auto alloc = [&](size_t bytes) { char* p = w; w += (bytes + 255) & ~(size_t)255; return p; };
  float* bufA = (float*)alloc((size_t)NL * NROWS * DIM * 4);
  float* bufB = (float*)alloc((size_t)NL * NROWS * DIM * 4);
  unsigned short* Gpb = (unsigned short*)alloc((size_t)NL * NROWS * DIM * 2);
  unsigned short* actb = (unsigned short*)alloc((size_t)NL * NROWS * DIM * 2);
  unsigned short* W1b = (unsigned short*)alloc((size_t)NL * DIM * DIM * 2);
  unsigned short* W2b = (unsigned short*)alloc((size_t)NL * DIM * DIM * 2);
  unsigned short* Pjb = (unsigned short*)alloc((size_t)PD * DIM * 2);
  float* sim  = (float*)alloc((size_t)NL * NCLS * CAP * CAP * 4);
  float* S    = (float*)alloc((size_t)NL * NCLS * CAP * CAP * 4);
  float* P    = (float*)alloc((size_t)NL * NROWS * PD * 4);
  float* invn = (float*)alloc((size_t)NL * NROWS * 4);
  float* dinv = (float*)alloc((size_t)NL * NCLS * CAP * 4);
  float* part = (float*)alloc((size_t)NL * PARTSZ * 4);
  float* bnsc = (float*)alloc((size_t)NL * 2 * DIM * 4);
  float* acc  = (float*)alloc(256);
  int* cnt  = (int*)alloc(NCLS * 4);
  int* offc = (int*)alloc((NCLS + 1) * 4);
  int* perm = (int*)alloc(NROWS * 4);
  int* clsp = (int*)alloc(NROWS * 4);
  int* t8   = (int*)alloc((size_t)NL * NROWS * 8 * 4);
  int* chunkCnt  = (int*)alloc(16 * NCLS * 4);
  int* chunkBase = (int*)alloc(16 * NCLS * 4);

  const float LAM_K = 64.f, LAM_Z = 16.f, SIGMA = 0.99f;
  const float cK = LAM_K / ((float)NROWS * (float)NROWS);
  const float cZ = LAM_Z / ((float)NROWS * (float)PD);
  const float cI = 1.f / ((float)NROWS * (float)NROWS);
  const long sAct = (long)NROWS * DIM;
  const long sW = (long)DIM * DIM;

  hipLaunchKernelGGL(k_zerof, dim3(1), dim3(64), 0, stream, acc, 4);
  hipLaunchKernelGGL(k_hist, dim3(16), dim3(256), 0, stream, labels, chunkCnt);
  hipLaunchKernelGGL(k_scan, dim3(1), dim3(64), 0, stream, chunkCnt, cnt, offc, chunkBase);
  hipLaunchKernelGGL(k_scatter, dim3(16), dim3(256), 0, stream, labels, chunkBase, perm, clsp);
  hipLaunchKernelGGL(k_tobf16, dim3((NL * DIM * DIM / 4 + 255) / 256), dim3(256), 0, stream,
                     (const float4*)fc1, (ushort4*)W1b, NL * DIM * DIM / 4);
  hipLaunchKernelGGL(k_tobf16, dim3((NL * DIM * DIM / 4 + 255) / 256), dim3(256), 0, stream,
                     (const float4*)fc2, (ushort4*)W2b, NL * DIM * DIM / 4);
  hipLaunchKernelGGL(k_tobf16, dim3((PD * DIM / 4 + 255) / 256), dim3(256), 0, stream,
                     (const float4*)proj, (ushort4*)Pjb, PD * DIM / 4);

  // --- all layers batched ---
  hipLaunchKernelGGL(k_prep, dim3(NROWS, NL), dim3(128), 0, stream, feats, perm, Gpb, invn);
  hipLaunchKernelGGL(k_sim, dim3(16, NCLS, NL), dim3(256), 0, stream, Gpb, invn, cnt, offc, sim);
  hipLaunchKernelGGL(k_topk, dim3(NROWS / 64, NL), dim3(64), 0, stream, sim, cnt, offc, clsp, t8);
  hipLaunchKernelGGL(k_buildS1, dim3(NCLS, CAP / 32, NL), dim3(256), 0, stream, sim, cnt, offc, t8, S, dinv);
  hipLaunchKernelGGL(k_buildS2, dim3(NCLS, CAP / 32, NL), dim3(256), 0, stream, S, dinv, cnt);

  // T1 = Gp @ w1^T
  hipLaunchKernelGGL(k_gemm_bf16, dim3(NROWS / 128, DIM / 64, NL), dim3(256), 0, stream,
                     (const short*)Gpb, (const short*)W1b, bufA, DIM, sAct, sW, (long)NROWS * DIM);
  // T2 = S @ T1
  hipLaunchKernelGGL(k_spmm4, dim3(NCLS, DIM / 256, 4 * NL), dim3(256), 0, stream, S, bufA,
                     (const float*)nullptr, (const int*)nullptr, bufB, (unsigned short*)nullptr, cnt, offc);
  // BN stats + relu -> bf16 T3
  hipLaunchKernelGGL(k_colstats, dim3(NROWS / 32, NL), dim3(256), 0, stream, bufB, part);
  hipLaunchKernelGGL(k_bnfin, dim3(DIM / 64, NL), dim3(64), 0, stream, part, gamma, beta, bnsc);
  hipLaunchKernelGGL(k_bnrelu, dim3(NROWS * DIM / 4 / 256, NL), dim3(256), 0, stream,
                     (const float4*)bufB, bnsc, (ushort4*)actb);
  // T4 = T3 @ w2^T
  hipLaunchKernelGGL(k_gemm_bf16, dim3(NROWS / 128, DIM / 64, NL), dim3(256), 0, stream,
                     (const short*)actb, (const short*)W2b, bufB, DIM, sAct, sW, (long)NROWS * DIM);
  // Z = S @ T4 + G -> bf16 (actb)
  hipLaunchKernelGGL(k_spmm4, dim3(NCLS, DIM / 256, 4 * NL), dim3(256), 0, stream, S, bufB,
                     feats, perm, (float*)nullptr, actb, cnt, offc);
  // P = l2norm(Z @ proj^T)
  hipLaunchKernelGGL(k_gemm_bf16, dim3(NROWS / 128, PD / 64, NL), dim3(256), 0, stream,
                     (const short*)actb, (const short*)Pjb, P, PD, sAct, 0L, (long)NROWS * PD);
  hipLaunchKernelGGL(k_rownormP, dim3(NROWS, NL), dim3(192), 0, stream, P);

  // losses
  hipLaunchKernelGGL(k_lossS, dim3(NCLS, 3), dim3(256), 0, stream, S, cnt, SIGMA, cK, cI, acc);
  hipLaunchKernelGGL(k_lossdiff, dim3(512, 2), dim3(256), 0, stream, P, NROWS * PD, cZ, acc);

  hipLaunchKernelGGL(k_final, dim3(1), dim3(64), 0, stream, acc, out);
}